// Round 5
// baseline (1348.496 us; speedup 1.0000x reference)
//
#include <hip/hip_runtime.h>
#include <hip/hip_bf16.h>
#include <math.h>

#define NH 8
#define DH 32
#define DIM 256
#define SEQ 2048
#define BATCH 4
#define NB 512            // SEQ / C
#define QKS 512           // q|k packed f32 row stride
#define VGS 320           // v|g packed bf16 row stride: 256 v | 24 g | 40 pad
#define SCALE 0.17677669529663687f  // DH^-0.5

typedef short short8v __attribute__((ext_vector_type(8)));
typedef float float4v __attribute__((ext_vector_type(4)));

__device__ __forceinline__ float sigmoidf_(float x){ return 1.f/(1.f+__expf(-x)); }
__device__ __forceinline__ ushort f2bf(float f){
  uint b = __float_as_uint(f);
  return (ushort)((b + 0x7fffu + ((b>>16)&1u)) >> 16);   // RNE
}
__device__ __forceinline__ float bf2f(ushort u){ return __uint_as_float(((uint)u)<<16); }
__device__ __forceinline__ void bf8_to_f32(const ushort* p, float* f){
  uint4 u = *(const uint4*)p;
  f[0]=__uint_as_float(u.x<<16); f[1]=__uint_as_float(u.x&0xffff0000u);
  f[2]=__uint_as_float(u.y<<16); f[3]=__uint_as_float(u.y&0xffff0000u);
  f[4]=__uint_as_float(u.z<<16); f[5]=__uint_as_float(u.z&0xffff0000u);
  f[6]=__uint_as_float(u.w<<16); f[7]=__uint_as_float(u.w&0xffff0000u);
}

// ---------------- copy (residual stream init) ----------------
__global__ void copy_f32(const float* __restrict__ in, float* __restrict__ out, int n4){
  int i = blockIdx.x*blockDim.x + threadIdx.x;
  if (i < n4) ((float4*)out)[i] = ((const float4*)in)[i];
}

// ---------------- weight packers ----------------
__global__ void build_wqk(const float* __restrict__ Wq, const float* __restrict__ Wk, float* __restrict__ out){
  int i = blockIdx.x*256 + threadIdx.x;          // 4*256*512
  if (i >= 4*256*QKS) return;
  int col = i & 511, rk = (i>>9)&255, l = i>>17;
  out[i] = (col < 256) ? Wq[((size_t)l*256+rk)*256+col] : Wk[((size_t)l*256+rk)*256+col-256];
}
__global__ void build_wvgT(const float* __restrict__ Wv, const float* __restrict__ Wg, ushort* __restrict__ out){
  int i = blockIdx.x*256 + threadIdx.x;          // 4*320*256 : out[l][n][k] = B[k][n]
  if (i >= 4*VGS*256) return;
  int k = i & 255, n = (i>>8)%VGS, l = i/(VGS*256);
  float v = 0.f;
  if      (n < 256) v = Wv[((size_t)l*256+k)*256+n];
  else if (n < 280) v = Wg[((size_t)l*256+k)*24 + (n-256)];
  out[i] = f2bf(v);
}
__global__ void build_wT(const float* __restrict__ in, ushort* __restrict__ out, int L, int K, int N){
  int i = blockIdx.x*256 + threadIdx.x;          // out[l][n][k] = in[l][k][n]
  if (i >= L*K*N) return;
  int k = i % K, n = (i/K) % N, l = i/(K*N);
  out[i] = f2bf(in[((size_t)l*K+k)*N+n]);
}

// ---------------- layernorm: one wave per row, dual f32+bf16 output ----------------
__global__ __launch_bounds__(256) void ln_k(const float* __restrict__ x, const float* __restrict__ g,
                                            const float* __restrict__ b, float* __restrict__ h,
                                            ushort* __restrict__ hb){
  int row  = blockIdx.x*4 + (threadIdx.x>>6);
  int lane = threadIdx.x & 63;
  int c = lane*4;
  const float* xr = x + (size_t)row*DIM + c;
  float4 v = *(const float4*)xr;
  float s = v.x+v.y+v.z+v.w;
  float q = v.x*v.x+v.y*v.y+v.z*v.z+v.w*v.w;
  #pragma unroll
  for (int off=32; off>0; off>>=1){ s += __shfl_xor(s, off); q += __shfl_xor(q, off); }
  float mean = s * (1.f/DIM);
  float var  = q * (1.f/DIM) - mean*mean;
  float rs = rsqrtf(var + 1e-5f);
  float4 gg = *(const float4*)(g + c);
  float4 bb = *(const float4*)(b + c);
  float4 o;
  o.x = (v.x-mean)*rs*gg.x + bb.x;
  o.y = (v.y-mean)*rs*gg.y + bb.y;
  o.z = (v.z-mean)*rs*gg.z + bb.z;
  o.w = (v.w-mean)*rs*gg.w + bb.w;
  *(float4*)(h + (size_t)row*DIM + c) = o;
  uint2 u;
  u.x = (uint)f2bf(o.x) | ((uint)f2bf(o.y)<<16);
  u.y = (uint)f2bf(o.z) | ((uint)f2bf(o.w)<<16);
  *(uint2*)&hb[(size_t)row*DIM + c] = u;
}

// ---------------- f32 GEMM (q|k path), guard-free, BK=32 ----------------
// tile 128x64, 256 threads, 8x4 per thread, register-prefetch double buffer
template<bool BIAS, bool LEAKY, bool ACC>
__global__ __launch_bounds__(256) void gemm_f32(const float* __restrict__ A, const float* __restrict__ B,
                                                const float* __restrict__ bias, float* __restrict__ C,
                                                int M, int N, int K){
  __shared__ float As[32][132];
  __shared__ float Bs[32][68];
  int tid = threadIdx.x;
  int m0 = blockIdx.x*128, n0 = blockIdx.y*64;
  int tx = tid & 15, ty = tid >> 4;
  int ar = tid >> 1;            // 0..127
  int ac = (tid & 1)*16;        // 0 or 16
  int bk = tid >> 3;            // 0..31
  int bn = (tid & 7)*8;         // 0..56
  const float* Ap = A + (size_t)(m0+ar)*K + ac;
  const float* Bp = B + (size_t)bk*N + n0 + bn;
  float4 apre[4], bpre[2];
  #pragma unroll
  for (int j=0;j<4;j++) apre[j] = *(const float4*)(Ap + 4*j);
  bpre[0] = *(const float4*)Bp;
  bpre[1] = *(const float4*)(Bp + 4);
  float acc[8][4];
  #pragma unroll
  for (int i=0;i<8;i++)
    #pragma unroll
    for (int j=0;j<4;j++) acc[i][j]=0.f;
  for (int k0=0; k0<K; k0+=32){
    #pragma unroll
    for (int j=0;j<4;j++){
      As[ac+4*j+0][ar]=apre[j].x; As[ac+4*j+1][ar]=apre[j].y;
      As[ac+4*j+2][ar]=apre[j].z; As[ac+4*j+3][ar]=apre[j].w;
    }
    *(float4*)&Bs[bk][bn]   = bpre[0];
    *(float4*)&Bs[bk][bn+4] = bpre[1];
    __syncthreads();
    if (k0 + 32 < K){
      #pragma unroll
      for (int j=0;j<4;j++) apre[j] = *(const float4*)(Ap + k0 + 32 + 4*j);
      bpre[0] = *(const float4*)(Bp + (size_t)(k0+32)*N);
      bpre[1] = *(const float4*)(Bp + (size_t)(k0+32)*N + 4);
    }
    #pragma unroll
    for (int kk=0;kk<32;kk++){
      float4 bv  = *(const float4*)&Bs[kk][tx*4];
      float4 av0 = *(const float4*)&As[kk][ty*8];
      float4 av1 = *(const float4*)&As[kk][ty*8+4];
      float av[8] = {av0.x,av0.y,av0.z,av0.w,av1.x,av1.y,av1.z,av1.w};
      float bw[4] = {bv.x,bv.y,bv.z,bv.w};
      #pragma unroll
      for (int i=0;i<8;i++)
        #pragma unroll
        for (int j=0;j<4;j++) acc[i][j] += av[i]*bw[j];
    }
    __syncthreads();
  }
  #pragma unroll
  for (int i=0;i<8;i++){
    int m = m0 + ty*8 + i;
    #pragma unroll
    for (int j=0;j<4;j++){
      int n = n0 + tx*4 + j;
      float val = acc[i][j];
      if (BIAS)  val += bias[n];
      if (LEAKY) val = val > 0.f ? val : 0.01f*val;
      float* cp = C + (size_t)m*N + n;
      if (ACC) val += *cp;
      *cp = val;
    }
  }
}

// ---------------- bf16 MFMA GEMM: C = act(A[M,K] @ Bt[N,K]^T + bias) ----------------
template<bool BIAS, bool LEAKY, bool ACC, bool OBF16>
__global__ __launch_bounds__(256) void gemm_bf16(const ushort* __restrict__ A, const ushort* __restrict__ Bt,
                                                 const float* __restrict__ bias, void* __restrict__ Cv,
                                                 int M, int N, int K){
  __shared__ ushort Al[128*64];
  __shared__ ushort Bl[64*64];
  int tid = threadIdx.x;
  int m0 = blockIdx.x*128, n0 = blockIdx.y*64;
  int w = tid>>6, lane = tid&63;
  int wm = w>>1, wn = w&1;
  float4v acc[4][2];
  #pragma unroll
  for (int i=0;i<4;i++)
    #pragma unroll
    for (int j=0;j<2;j++) acc[i][j] = (float4v){0.f,0.f,0.f,0.f};
  for (int k0=0; k0<K; k0+=64){
    #pragma unroll
    for (int i=0;i<4;i++){
      int id = tid + 256*i;
      int r = id>>3, c = id&7;
      *(uint4*)&Al[r*64 + ((c ^ (r&7))*8)] = *(const uint4*)&A[(size_t)(m0+r)*K + k0 + c*8];
    }
    #pragma unroll
    for (int i=0;i<2;i++){
      int id = tid + 256*i;
      int r = id>>3, c = id&7;
      *(uint4*)&Bl[r*64 + ((c ^ (r&7))*8)] = *(const uint4*)&Bt[(size_t)(n0+r)*K + k0 + c*8];
    }
    __syncthreads();
    #pragma unroll
    for (int kk=0; kk<2; ++kk){
      short8v a[4], bfr[2];
      #pragma unroll
      for (int mf=0; mf<4; mf++){
        int r = wm*64 + mf*16 + (lane&15);
        int c = (kk*4 + (lane>>4)) ^ (r&7);
        a[mf] = *(short8v*)&Al[r*64 + c*8];
      }
      #pragma unroll
      for (int nf=0; nf<2; nf++){
        int r = wn*32 + nf*16 + (lane&15);
        int c = (kk*4 + (lane>>4)) ^ (r&7);
        bfr[nf] = *(short8v*)&Bl[r*64 + c*8];
      }
      #pragma unroll
      for (int mf=0; mf<4; mf++)
        #pragma unroll
        for (int nf=0; nf<2; nf++)
          acc[mf][nf] = __builtin_amdgcn_mfma_f32_16x16x32_bf16(a[mf], bfr[nf], acc[mf][nf], 0, 0, 0);
    }
    __syncthreads();
  }
  #pragma unroll
  for (int nf=0; nf<2; nf++){
    int col = n0 + wn*32 + nf*16 + (lane&15);
    float bv = BIAS ? bias[col] : 0.f;
    #pragma unroll
    for (int mf=0; mf<4; mf++){
      #pragma unroll
      for (int r=0; r<4; r++){
        int row = m0 + wm*64 + mf*16 + (lane>>4)*4 + r;
        float vv = acc[mf][nf][r];
        if (BIAS) vv += bv;
        if (LEAKY) vv = vv > 0.f ? vv : 0.01f*vv;
        if (OBF16) ((ushort*)Cv)[(size_t)row*N + col] = f2bf(vv);
        else {
          float* C = (float*)Cv;
          if (ACC) vv += C[(size_t)row*N + col];
          C[(size_t)row*N + col] = vv;
        }
      }
    }
  }
}

// ---------------- mean-pool K/V blocks (C=4), output [b][h][n][32] f32 ----------------
__global__ void pool_k(const float* __restrict__ qk, const ushort* __restrict__ vg,
                       float* __restrict__ kc, float* __restrict__ vc){
  int i = blockIdx.x*256 + threadIdx.x;       // 0 .. B*H*NB*32-1
  if (i >= BATCH*NH*NB*DH) return;
  int d = i & 31, n = (i >> 5) & 511, h = (i >> 14) & 7, b = i >> 17;
  size_t kb = ((size_t)(b*SEQ + n*4))*QKS + 256 + h*DH + d;
  kc[i] = 0.25f*(qk[kb] + qk[kb+QKS] + qk[kb+2*QKS] + qk[kb+3*QKS]);
  size_t vb = ((size_t)(b*SEQ + n*4))*VGS + h*DH + d;
  vc[i] = 0.25f*(bf2f(vg[vb]) + bf2f(vg[vb+VGS]) + bf2f(vg[vb+2*VGS]) + bf2f(vg[vb+3*VGS]));
}

// ---------------- fused NSA attention v3: paired groups, uniform weight ----------------
// 64 token-groups of 32; block e: pair (gA=63-p, gB=p), p=e>>5; bh=(e&7)+8*((e>>3)&3)
// (same-bh blocks share an XCD slot -> kc/vc L2-local). 4 waves; 8-way n-split via
// half-waves (lane = tok + 32*sub, split = w*2+sub). Per-block weight constant (65).
// Partials combine in LDS (max-free softmax is linear); scores bitwise-identical to
// the monolithic loop (same d-ordering), so the top-k argmax is exactly preserved.
__global__ __launch_bounds__(256, 4) void nsa_attn(
    const float* __restrict__ qk, const ushort* __restrict__ vg,
    const float* __restrict__ kc, const float* __restrict__ vc,
    ushort* __restrict__ o)
{
  __shared__ float red[8*32*36];   // 36 KiB: [split][tok][32 acc + l + best + bestn + pad]
  int e = blockIdx.x;
  int p  = e >> 5;                          // pair index 0..31
  int bh = (e & 7) + ((e >> 3) & 3) * 8;
  int hh = bh & 7, b = bh >> 3;
  int tid = threadIdx.x;
  int w = tid >> 6, lane = tid & 63;
  int tok = lane & 31, sub = lane >> 5;
  int split = w*2 + sub;                    // 0..7, ascending n
  const float* kcg = kc + ((size_t)(b*NH + hh)*NB)*DH;
  const float* vcg = vc + ((size_t)(b*NH + hh)*NB)*DH;
  const float*  kbase = qk + (size_t)b*SEQ*QKS + 256 + hh*DH;
  const ushort* vbase = vg + (size_t)b*SEQ*VGS + hh*DH;

  #pragma unroll
  for (int half = 0; half < 2; ++half){
    int g = half ? p : (63 - p);
    int t = g*32 + tok;
    size_t rowq = ((size_t)b*SEQ + t)*QKS + hh*DH;
    float qv[32];
    #pragma unroll
    for (int d=0; d<32; d+=4){
      float4 t4 = *(const float4*)(qk + rowq + d);
      qv[d]=t4.x; qv[d+1]=t4.y; qv[d+2]=t4.z; qv[d+3]=t4.w;
    }
    int own = t >> 2, nvis = (t+1) >> 2;

    // ---- phase 1: compressed-branch partial over this split's n-range
    int chunk = g + 1;                      // nvis_max = 8(g+1) over 8 splits
    int n0 = split*chunk, n1 = n0 + chunk;
    float l = 0.f, best = -1e30f;
    int bestn = -1;
    float acc[32];
    #pragma unroll
    for (int d=0;d<32;d++) acc[d]=0.f;
    auto body = [&](int n){
      const float4* kp = (const float4*)(kcg + (size_t)n*DH);
      float kv[32];
      #pragma unroll
      for (int d8=0; d8<8; d8++){
        float4 t4 = kp[d8];
        kv[4*d8]=t4.x; kv[4*d8+1]=t4.y; kv[4*d8+2]=t4.z; kv[4*d8+3]=t4.w;
      }
      float s = 0.f;
      #pragma unroll
      for (int d=0; d<32; d++) s += qv[d]*kv[d];     // same ordering as ever -> bitwise-same s
      s *= SCALE;
      bool act = (n < nvis);
      if (act && n != own && s > best){ best = s; bestn = n; }
      float pp = act ? __expf(s) : 0.f;
      l += pp;
      const float4* vp = (const float4*)(vcg + (size_t)n*DH);
      #pragma unroll
      for (int d8=0; d8<8; d8++){
        float4 vv = vp[d8];
        acc[4*d8]   += pp*vv.x; acc[4*d8+1] += pp*vv.y;
        acc[4*d8+2] += pp*vv.z; acc[4*d8+3] += pp*vv.w;
      }
    };
    int n = n0;
    if (chunk & 1){ body(n); n++; }
    for (; n < n1; n += 2){ body(n); body(n+1); }

    float4* myr = (float4*)&red[(split*32 + tok)*36];
    #pragma unroll
    for (int d8=0; d8<8; d8++) myr[d8] = make_float4(acc[4*d8],acc[4*d8+1],acc[4*d8+2],acc[4*d8+3]);
    myr[8] = make_float4(l, best, __int_as_float(bestn), 0.f);
    __syncthreads();

    // ---- phase 2: wave w finalizes tokens [8w, 8w+8) (active lanes 8w..8w+7)
    if ((lane >> 3) == w){
      float ll = 0.f, bb = -1e30f;
      int bn = (own==0) ? 1 : 0;            // jax top_k fallback
      float out[32];
      #pragma unroll
      for (int d=0;d<32;d++) out[d]=0.f;
      #pragma unroll
      for (int sp=0; sp<8; ++sp){           // ascending split = ascending n: tie-break ok
        const float4* r = (const float4*)&red[(sp*32 + lane)*36];
        #pragma unroll
        for (int d8=0; d8<8; d8++){
          float4 a4 = r[d8];
          out[4*d8]+=a4.x; out[4*d8+1]+=a4.y; out[4*d8+2]+=a4.z; out[4*d8+3]+=a4.w;
        }
        float4 m4 = r[8];
        ll += m4.x;
        if (m4.y > bb){ bb = m4.y; bn = __float_as_int(m4.z); }
      }
      const ushort* gr = vg + ((size_t)b*SEQ + t)*VGS + 256;
      float g0 = sigmoidf_(bf2f(gr[hh])), g1 = sigmoidf_(bf2f(gr[8+hh])), g2 = sigmoidf_(bf2f(gr[16+hh]));
      float inv = (nvis > 0) ? g0/ll : 0.f;
      #pragma unroll
      for (int d=0;d<32;d++) out[d] *= inv;

      // ---- selection branch: own block + best block, causal token mask
      float s2[8];
      float m2 = -1e30f;
      #pragma unroll
      for (int ki=0; ki<8; ++ki){
        int tt = (ki<4 ? own : bn)*4 + (ki&3);
        float s = -1e30f;
        if (tt <= t){
          const float* kr = kbase + (size_t)tt*QKS;
          float sv = 0.f;
          #pragma unroll
          for (int d=0; d<32; d+=4){
            float4 kv = *(const float4*)(kr + d);
            sv += qv[d]*kv.x + qv[d+1]*kv.y + qv[d+2]*kv.z + qv[d+3]*kv.w;
          }
          s = sv*SCALE;
          m2 = fmaxf(m2, s);
        }
        s2[ki] = s;
      }
      float l2 = 0.f;
      #pragma unroll
      for (int ki=0; ki<8; ++ki)
        if (s2[ki] > -1e29f) l2 += __expf(s2[ki] - m2);
      float inv2 = g1/l2;                   // l2 >= 1 (self token visible)
      #pragma unroll
      for (int ki=0; ki<8; ++ki){
        int tt = (ki<4 ? own : bn)*4 + (ki&3);
        if (tt <= t){
          float pw = __expf(s2[ki] - m2) * inv2;
          float vvv[32];
          #pragma unroll
          for (int d=0; d<32; d+=8) bf8_to_f32(vbase + (size_t)tt*VGS + d, &vvv[d]);
          #pragma unroll
          for (int d=0; d<32; d++) out[d] += pw*vvv[d];
        }
      }

      // ---- sliding window (W=2): tokens t-1, t
      int tp = (t>0) ? t-1 : 0;
      const float* ka = kbase + (size_t)tp*QKS;
      const float* kb2= kbase + (size_t)t *QKS;
      float sa=0.f, sb=0.f;
      #pragma unroll
      for (int d=0; d<32; d+=4){
        float4 k1 = *(const float4*)(ka + d);
        float4 k2 = *(const float4*)(kb2 + d);
        sa += qv[d]*k1.x + qv[d+1]*k1.y + qv[d+2]*k1.z + qv[d+3]*k1.w;
        sb += qv[d]*k2.x + qv[d+1]*k2.y + qv[d+2]*k2.z + qv[d+3]*k2.w;
      }
      sa *= SCALE; sb *= SCALE;
      float m3 = (t>0) ? fmaxf(sa, sb) : sb;
      float pa = (t>0) ? __expf(sa-m3) : 0.f;
      float pb = __expf(sb-m3);
      float inv3 = g2/(pa+pb);
      float va[32], vbv[32];
      #pragma unroll
      for (int d=0; d<32; d+=8){
        bf8_to_f32(vbase + (size_t)tp*VGS + d, &va[d]);
        bf8_to_f32(vbase + (size_t)t *VGS + d, &vbv[d]);
      }
      ushort* orow = o + ((size_t)b*SEQ + t)*DIM + hh*DH;
      #pragma unroll
      for (int d=0; d<32; d+=8){
        float r0[8];
        #pragma unroll
        for (int j=0;j<8;j++) r0[j] = out[d+j] + (pa*va[d+j] + pb*vbv[d+j])*inv3;
        uint4 u;
        u.x = (uint)f2bf(r0[0]) | ((uint)f2bf(r0[1])<<16);
        u.y = (uint)f2bf(r0[2]) | ((uint)f2bf(r0[3])<<16);
        u.z = (uint)f2bf(r0[4]) | ((uint)f2bf(r0[5])<<16);
        u.w = (uint)f2bf(r0[6]) | ((uint)f2bf(r0[7])<<16);
        *(uint4*)&orow[d] = u;
      }
    }
    __syncthreads();   // red reused by next half
  }
}

extern "C" void kernel_launch(void* const* d_in, const int* in_sizes, int n_in,
                              void* d_out, int out_size, void* d_ws, size_t ws_size,
                              hipStream_t stream) {
  const float* x_in   = (const float*)d_in[0];
  const float* ln_a_g = (const float*)d_in[1];
  const float* ln_a_b = (const float*)d_in[2];
  const float* Wq     = (const float*)d_in[3];
  const float* Wk     = (const float*)d_in[4];
  const float* Wv     = (const float*)d_in[5];
  const float* Wg     = (const float*)d_in[6];
  const float* Wo     = (const float*)d_in[7];
  const float* ln_f_g = (const float*)d_in[8];
  const float* ln_f_b = (const float*)d_in[9];
  const float* W1     = (const float*)d_in[10];
  const float* b1     = (const float*)d_in[11];
  const float* W2     = (const float*)d_in[12];
  const float* b2     = (const float*)d_in[13];

  float* xout = (float*)d_out;             // running residual stream [8192][256] f32
  float* ws = (float*)d_ws;
  const size_t NTOK = (size_t)BATCH*SEQ;   // 8192
  float* h    = ws;                                    // [8192][256] f32
  float* qkb  = h    + NTOK*DIM;                       // [8192][512] f32
  float* kcb  = qkb  + NTOK*QKS;                       // [4][8][512][32] f32
  float* vcb  = kcb  + (size_t)BATCH*NH*NB*DH;
  float* wqk  = vcb  + (size_t)BATCH*NH*NB*DH;         // [4][256][512] f32
  ushort* hb   = (ushort*)(wqk + (size_t)4*DIM*QKS);   // [8192][256] bf16
  ushort* vgu  = hb   + NTOK*DIM;                      // [8192][320] bf16
  ushort* obu  = vgu  + NTOK*VGS;                      // [8192][256] bf16
  ushort* midu = obu  + NTOK*DIM;                      // [8192][512] bf16
  ushort* wvgT = midu + NTOK*512;                      // [4][320][256] bf16
  ushort* woT  = wvgT + (size_t)4*VGS*DIM;             // [4][256][256] bf16
  ushort* w1T  = woT  + (size_t)4*DIM*DIM;             // [2][512][256] bf16
  ushort* w2T  = w1T  + (size_t)2*512*DIM;             // [2][256][512] bf16

  copy_f32<<<2048, 256, 0, stream>>>(x_in, xout, (int)(NTOK*DIM/4));
  build_wqk <<<(4*256*QKS+255)/256, 256, 0, stream>>>(Wq, Wk, wqk);
  build_wvgT<<<(4*VGS*256+255)/256, 256, 0, stream>>>(Wv, Wg, wvgT);
  build_wT  <<<(4*256*256+255)/256, 256, 0, stream>>>(Wo, woT, 4, 256, 256);
  build_wT  <<<(2*256*512+255)/256, 256, 0, stream>>>(W1, w1T, 2, 256, 512);
  build_wT  <<<(2*512*256+255)/256, 256, 0, stream>>>(W2, w2T, 2, 512, 256);

  dim3 gqk(64,8), gvg(64,5), g4(64,4), g8(64,8);
  for (int i=0;i<4;i++){
    ln_k<<<2048,256,0,stream>>>(xout, ln_a_g + i*DIM, ln_a_b + i*DIM, h, hb);
    gemm_f32<false,false,false><<<gqk,256,0,stream>>>(h, wqk + (size_t)i*DIM*QKS, nullptr, qkb, 8192,QKS,256);
    gemm_bf16<false,false,false,true><<<gvg,256,0,stream>>>(hb, wvgT + (size_t)i*VGS*DIM, nullptr, vgu, 8192,VGS,256);
    pool_k<<<2048,256,0,stream>>>(qkb, vgu, kcb, vcb);
    nsa_attn<<<1024,256,0,stream>>>(qkb, vgu, kcb, vcb, obu);
    gemm_bf16<false,false,true,false><<<g4,256,0,stream>>>(obu, woT + (size_t)i*DIM*DIM, nullptr, xout, 8192,DIM,256);
    if (i & 1){
      int l = i >> 1;
      ln_k<<<2048,256,0,stream>>>(xout, ln_f_g + l*DIM, ln_f_b + l*DIM, h, hb);
      gemm_bf16<true,true,false,true><<<g8,256,0,stream>>>(hb,   w1T + (size_t)l*512*DIM, b1 + l*512, midu, 8192,512,256);
      gemm_bf16<true,false,true,false><<<g4,256,0,stream>>>(midu, w2T + (size_t)l*DIM*512, b2 + l*DIM, xout, 8192,DIM,512);
    }
  }
}

// Round 6
// 951.245 us; speedup vs baseline: 1.4176x; 1.4176x over previous
//
#include <hip/hip_runtime.h>
#include <hip/hip_bf16.h>
#include <math.h>

#define NH 8
#define DH 32
#define DIM 256
#define SEQ 2048
#define BATCH 4
#define NB 512            // SEQ / C
#define QKS 512           // q|k packed f32 row stride
#define VGS 320           // v|g packed bf16 row stride: 256 v | 24 g | 40 pad
#define SCALE 0.17677669529663687f  // DH^-0.5

typedef short short8v __attribute__((ext_vector_type(8)));
typedef float float4v __attribute__((ext_vector_type(4)));

__device__ __forceinline__ float sigmoidf_(float x){ return 1.f/(1.f+__expf(-x)); }
__device__ __forceinline__ ushort f2bf(float f){
  uint b = __float_as_uint(f);
  return (ushort)((b + 0x7fffu + ((b>>16)&1u)) >> 16);   // RNE
}
__device__ __forceinline__ float bf2f(ushort u){ return __uint_as_float(((uint)u)<<16); }
__device__ __forceinline__ float bflo(uint u){ return __uint_as_float(u<<16); }
__device__ __forceinline__ float bfhi(uint u){ return __uint_as_float(u & 0xffff0000u); }
__device__ __forceinline__ uint pk2(float a, float b){ return (uint)f2bf(a) | ((uint)f2bf(b)<<16); }
__device__ __forceinline__ void bf8_to_f32(const ushort* p, float* f){
  uint4 u = *(const uint4*)p;
  f[0]=bflo(u.x); f[1]=bfhi(u.x);
  f[2]=bflo(u.y); f[3]=bfhi(u.y);
  f[4]=bflo(u.z); f[5]=bfhi(u.z);
  f[6]=bflo(u.w); f[7]=bfhi(u.w);
}

// ---------------- copy (residual stream init) ----------------
__global__ void copy_f32(const float* __restrict__ in, float* __restrict__ out, int n4){
  int i = blockIdx.x*blockDim.x + threadIdx.x;
  if (i < n4) ((float4*)out)[i] = ((const float4*)in)[i];
}

// ---------------- weight packers ----------------
__global__ void build_wqk(const float* __restrict__ Wq, const float* __restrict__ Wk, float* __restrict__ out){
  int i = blockIdx.x*256 + threadIdx.x;          // 4*256*512
  if (i >= 4*256*QKS) return;
  int col = i & 511, rk = (i>>9)&255, l = i>>17;
  out[i] = (col < 256) ? Wq[((size_t)l*256+rk)*256+col] : Wk[((size_t)l*256+rk)*256+col-256];
}
__global__ void build_wvgT(const float* __restrict__ Wv, const float* __restrict__ Wg, ushort* __restrict__ out){
  int i = blockIdx.x*256 + threadIdx.x;          // 4*320*256 : out[l][n][k] = B[k][n]
  if (i >= 4*VGS*256) return;
  int k = i & 255, n = (i>>8)%VGS, l = i/(VGS*256);
  float v = 0.f;
  if      (n < 256) v = Wv[((size_t)l*256+k)*256+n];
  else if (n < 280) v = Wg[((size_t)l*256+k)*24 + (n-256)];
  out[i] = f2bf(v);
}
__global__ void build_wT(const float* __restrict__ in, ushort* __restrict__ out, int L, int K, int N){
  int i = blockIdx.x*256 + threadIdx.x;          // out[l][n][k] = in[l][k][n]
  if (i >= L*K*N) return;
  int k = i % K, n = (i/K) % N, l = i/(K*N);
  out[i] = f2bf(in[((size_t)l*K+k)*N+n]);
}

// ---------------- layernorm: one wave per row, dual f32+bf16 output ----------------
__global__ __launch_bounds__(256) void ln_k(const float* __restrict__ x, const float* __restrict__ g,
                                            const float* __restrict__ b, float* __restrict__ h,
                                            ushort* __restrict__ hb){
  int row  = blockIdx.x*4 + (threadIdx.x>>6);
  int lane = threadIdx.x & 63;
  int c = lane*4;
  const float* xr = x + (size_t)row*DIM + c;
  float4 v = *(const float4*)xr;
  float s = v.x+v.y+v.z+v.w;
  float q = v.x*v.x+v.y*v.y+v.z*v.z+v.w*v.w;
  #pragma unroll
  for (int off=32; off>0; off>>=1){ s += __shfl_xor(s, off); q += __shfl_xor(q, off); }
  float mean = s * (1.f/DIM);
  float var  = q * (1.f/DIM) - mean*mean;
  float rs = rsqrtf(var + 1e-5f);
  float4 gg = *(const float4*)(g + c);
  float4 bb = *(const float4*)(b + c);
  float4 o;
  o.x = (v.x-mean)*rs*gg.x + bb.x;
  o.y = (v.y-mean)*rs*gg.y + bb.y;
  o.z = (v.z-mean)*rs*gg.z + bb.z;
  o.w = (v.w-mean)*rs*gg.w + bb.w;
  *(float4*)(h + (size_t)row*DIM + c) = o;
  uint2 u;
  u.x = pk2(o.x, o.y);
  u.y = pk2(o.z, o.w);
  *(uint2*)&hb[(size_t)row*DIM + c] = u;
}

// ---------------- f32 GEMM (q|k path), guard-free, BK=32 ----------------
template<bool BIAS, bool LEAKY, bool ACC>
__global__ __launch_bounds__(256) void gemm_f32(const float* __restrict__ A, const float* __restrict__ B,
                                                const float* __restrict__ bias, float* __restrict__ C,
                                                int M, int N, int K){
  __shared__ float As[32][132];
  __shared__ float Bs[32][68];
  int tid = threadIdx.x;
  int m0 = blockIdx.x*128, n0 = blockIdx.y*64;
  int tx = tid & 15, ty = tid >> 4;
  int ar = tid >> 1;            // 0..127
  int ac = (tid & 1)*16;        // 0 or 16
  int bk = tid >> 3;            // 0..31
  int bn = (tid & 7)*8;         // 0..56
  const float* Ap = A + (size_t)(m0+ar)*K + ac;
  const float* Bp = B + (size_t)bk*N + n0 + bn;
  float4 apre[4], bpre[2];
  #pragma unroll
  for (int j=0;j<4;j++) apre[j] = *(const float4*)(Ap + 4*j);
  bpre[0] = *(const float4*)Bp;
  bpre[1] = *(const float4*)(Bp + 4);
  float acc[8][4];
  #pragma unroll
  for (int i=0;i<8;i++)
    #pragma unroll
    for (int j=0;j<4;j++) acc[i][j]=0.f;
  for (int k0=0; k0<K; k0+=32){
    #pragma unroll
    for (int j=0;j<4;j++){
      As[ac+4*j+0][ar]=apre[j].x; As[ac+4*j+1][ar]=apre[j].y;
      As[ac+4*j+2][ar]=apre[j].z; As[ac+4*j+3][ar]=apre[j].w;
    }
    *(float4*)&Bs[bk][bn]   = bpre[0];
    *(float4*)&Bs[bk][bn+4] = bpre[1];
    __syncthreads();
    if (k0 + 32 < K){
      #pragma unroll
      for (int j=0;j<4;j++) apre[j] = *(const float4*)(Ap + k0 + 32 + 4*j);
      bpre[0] = *(const float4*)(Bp + (size_t)(k0+32)*N);
      bpre[1] = *(const float4*)(Bp + (size_t)(k0+32)*N + 4);
    }
    #pragma unroll
    for (int kk=0;kk<32;kk++){
      float4 bv  = *(const float4*)&Bs[kk][tx*4];
      float4 av0 = *(const float4*)&As[kk][ty*8];
      float4 av1 = *(const float4*)&As[kk][ty*8+4];
      float av[8] = {av0.x,av0.y,av0.z,av0.w,av1.x,av1.y,av1.z,av1.w};
      float bw[4] = {bv.x,bv.y,bv.z,bv.w};
      #pragma unroll
      for (int i=0;i<8;i++)
        #pragma unroll
        for (int j=0;j<4;j++) acc[i][j] += av[i]*bw[j];
    }
    __syncthreads();
  }
  #pragma unroll
  for (int i=0;i<8;i++){
    int m = m0 + ty*8 + i;
    #pragma unroll
    for (int j=0;j<4;j++){
      int n = n0 + tx*4 + j;
      float val = acc[i][j];
      if (BIAS)  val += bias[n];
      if (LEAKY) val = val > 0.f ? val : 0.01f*val;
      float* cp = C + (size_t)m*N + n;
      if (ACC) val += *cp;
      *cp = val;
    }
  }
}

// ---------------- bf16 MFMA GEMM: C = act(A[M,K] @ Bt[N,K]^T + bias) ----------------
template<bool BIAS, bool LEAKY, bool ACC, bool OBF16>
__global__ __launch_bounds__(256) void gemm_bf16(const ushort* __restrict__ A, const ushort* __restrict__ Bt,
                                                 const float* __restrict__ bias, void* __restrict__ Cv,
                                                 int M, int N, int K){
  __shared__ ushort Al[128*64];
  __shared__ ushort Bl[64*64];
  int tid = threadIdx.x;
  int m0 = blockIdx.x*128, n0 = blockIdx.y*64;
  int w = tid>>6, lane = tid&63;
  int wm = w>>1, wn = w&1;
  float4v acc[4][2];
  #pragma unroll
  for (int i=0;i<4;i++)
    #pragma unroll
    for (int j=0;j<2;j++) acc[i][j] = (float4v){0.f,0.f,0.f,0.f};
  for (int k0=0; k0<K; k0+=64){
    #pragma unroll
    for (int i=0;i<4;i++){
      int id = tid + 256*i;
      int r = id>>3, c = id&7;
      *(uint4*)&Al[r*64 + ((c ^ (r&7))*8)] = *(const uint4*)&A[(size_t)(m0+r)*K + k0 + c*8];
    }
    #pragma unroll
    for (int i=0;i<2;i++){
      int id = tid + 256*i;
      int r = id>>3, c = id&7;
      *(uint4*)&Bl[r*64 + ((c ^ (r&7))*8)] = *(const uint4*)&Bt[(size_t)(n0+r)*K + k0 + c*8];
    }
    __syncthreads();
    #pragma unroll
    for (int kk=0; kk<2; ++kk){
      short8v a[4], bfr[2];
      #pragma unroll
      for (int mf=0; mf<4; mf++){
        int r = wm*64 + mf*16 + (lane&15);
        int c = (kk*4 + (lane>>4)) ^ (r&7);
        a[mf] = *(short8v*)&Al[r*64 + c*8];
      }
      #pragma unroll
      for (int nf=0; nf<2; nf++){
        int r = wn*32 + nf*16 + (lane&15);
        int c = (kk*4 + (lane>>4)) ^ (r&7);
        bfr[nf] = *(short8v*)&Bl[r*64 + c*8];
      }
      #pragma unroll
      for (int mf=0; mf<4; mf++)
        #pragma unroll
        for (int nf=0; nf<2; nf++)
          acc[mf][nf] = __builtin_amdgcn_mfma_f32_16x16x32_bf16(a[mf], bfr[nf], acc[mf][nf], 0, 0, 0);
    }
    __syncthreads();
  }
  #pragma unroll
  for (int nf=0; nf<2; nf++){
    int col = n0 + wn*32 + nf*16 + (lane&15);
    float bv = BIAS ? bias[col] : 0.f;
    #pragma unroll
    for (int mf=0; mf<4; mf++){
      #pragma unroll
      for (int r=0; r<4; r++){
        int row = m0 + wm*64 + mf*16 + (lane>>4)*4 + r;
        float vv = acc[mf][nf][r];
        if (BIAS) vv += bv;
        if (LEAKY) vv = vv > 0.f ? vv : 0.01f*vv;
        if (OBF16) ((ushort*)Cv)[(size_t)row*N + col] = f2bf(vv);
        else {
          float* C = (float*)Cv;
          if (ACC) vv += C[(size_t)row*N + col];
          C[(size_t)row*N + col] = vv;
        }
      }
    }
  }
}

// ---------------- mean-pool K/V blocks (C=4), output [b][h][n][32] f32 ----------------
__global__ void pool_k(const float* __restrict__ qk, const ushort* __restrict__ vg,
                       float* __restrict__ kc, float* __restrict__ vc){
  int i = blockIdx.x*256 + threadIdx.x;       // 0 .. B*H*NB*32-1
  if (i >= BATCH*NH*NB*DH) return;
  int d = i & 31, n = (i >> 5) & 511, h = (i >> 14) & 7, b = i >> 17;
  size_t kb = ((size_t)(b*SEQ + n*4))*QKS + 256 + h*DH + d;
  kc[i] = 0.25f*(qk[kb] + qk[kb+QKS] + qk[kb+2*QKS] + qk[kb+3*QKS]);
  size_t vb = ((size_t)(b*SEQ + n*4))*VGS + h*DH + d;
  vc[i] = 0.25f*(bf2f(vg[vb]) + bf2f(vg[vb+VGS]) + bf2f(vg[vb+2*VGS]) + bf2f(vg[vb+3*VGS]));
}

// ---------------- fused NSA attention v4: 16 groups x 128 tokens, 2 tok/lane ----------------
// Block e: hh=e&7 (XCD slot), b=(e>>3)&3, gc=(e>>5)&7; g = e<256 ? 15-gc : gc.
// Blocks e and e+256 share (b,h) and have complementary g (sum 17) -> land on the
// same CU (2 blocks/CU) with constant total weight; same XCD -> kc/vc L2-local.
// 4 waves split n contiguously (chunk = 8(g+1)); lane owns tokens t0=g*128+lane and
// t0+64. Scores use the exact d-sequential f32 dot (bitwise = prior rounds) so the
// top-k argmax is preserved; oc partials staged bf16 in LDS (value path only).
__global__ __launch_bounds__(256, 2) void nsa_attn(
    const float* __restrict__ qk, const ushort* __restrict__ vg,
    const float* __restrict__ kc, const float* __restrict__ vc,
    ushort* __restrict__ o)
{
  __shared__ ushort accs[4*128*40];   // 40 KB: bf16 oc partials, stride 40 (16B-aligned rows)
  __shared__ float4 meta[4*128];      // 8 KB: (l, best, bestn, -) f32-exact
  int e = blockIdx.x;
  int hh = e & 7;
  int b  = (e >> 3) & 3;
  int gc = (e >> 5) & 7;
  int g  = (e < 256) ? (15 - gc) : gc;
  int tid = threadIdx.x;
  int w = tid >> 6, lane = tid & 63;
  int t0 = g*128 + lane;
  int t1 = t0 + 64;
  const float* kcg = kc + ((size_t)(b*NH + hh)*NB)*DH;
  const float* vcg = vc + ((size_t)(b*NH + hh)*NB)*DH;
  const float*  kbase = qk + (size_t)b*SEQ*QKS + 256 + hh*DH;
  const ushort* vbase = vg + (size_t)b*SEQ*VGS + hh*DH;

  float qv0[32], qv1[32];
  {
    size_t r0 = ((size_t)b*SEQ + t0)*QKS + hh*DH;
    size_t r1 = ((size_t)b*SEQ + t1)*QKS + hh*DH;
    #pragma unroll
    for (int d=0; d<32; d+=4){
      float4 a4 = *(const float4*)(qk + r0 + d);
      float4 b4 = *(const float4*)(qk + r1 + d);
      qv0[d]=a4.x; qv0[d+1]=a4.y; qv0[d+2]=a4.z; qv0[d+3]=a4.w;
      qv1[d]=b4.x; qv1[d+1]=b4.y; qv1[d+2]=b4.z; qv1[d+3]=b4.w;
    }
  }
  int own0 = t0>>2, nvis0 = (t0+1)>>2;
  int own1 = t1>>2, nvis1 = (t1+1)>>2;

  // ---- phase 1: compressed-branch partials over this wave's n-chunk, 2 tokens/lane
  int chunk = 8*(g+1);
  int n0 = w*chunk, n1 = n0 + chunk;
  float l0=0.f, l1=0.f, best0=-1e30f, best1=-1e30f;
  int bn0=-1, bn1=-1;
  float acc0[32], acc1[32];
  #pragma unroll
  for (int d=0;d<32;d++){ acc0[d]=0.f; acc1[d]=0.f; }
  for (int n=n0; n<n1; ++n){
    const float4* kp = (const float4*)(kcg + (size_t)n*DH);   // wave-uniform row
    const float4* vp = (const float4*)(vcg + (size_t)n*DH);
    float kv[32], vv[32];
    #pragma unroll
    for (int d8=0; d8<8; d8++){
      float4 a4 = kp[d8]; float4 b4 = vp[d8];
      kv[4*d8]=a4.x; kv[4*d8+1]=a4.y; kv[4*d8+2]=a4.z; kv[4*d8+3]=a4.w;
      vv[4*d8]=b4.x; vv[4*d8+1]=b4.y; vv[4*d8+2]=b4.z; vv[4*d8+3]=b4.w;
    }
    float s0=0.f, s1=0.f;
    #pragma unroll
    for (int d=0; d<32; d++){ s0 += qv0[d]*kv[d]; s1 += qv1[d]*kv[d]; }  // d-sequential: bitwise-stable
    s0 *= SCALE; s1 *= SCALE;
    bool a0 = (n < nvis0), a1 = (n < nvis1);
    if (a0 && n != own0 && s0 > best0){ best0 = s0; bn0 = n; }  // strict > = lowest-index tie-break
    if (a1 && n != own1 && s1 > best1){ best1 = s1; bn1 = n; }
    float p0 = a0 ? __expf(s0) : 0.f;   // max-free: |s| small, exp safe
    float p1 = a1 ? __expf(s1) : 0.f;
    l0 += p0; l1 += p1;
    #pragma unroll
    for (int d=0; d<32; d++){ acc0[d] += p0*vv[d]; acc1[d] += p1*vv[d]; }
  }
  {
    ushort* r0 = &accs[(w*128 + lane)*40];
    ushort* r1 = &accs[(w*128 + lane + 64)*40];
    #pragma unroll
    for (int q8=0; q8<4; q8++){
      uint4 u0, u1;
      u0.x = pk2(acc0[8*q8+0],acc0[8*q8+1]); u0.y = pk2(acc0[8*q8+2],acc0[8*q8+3]);
      u0.z = pk2(acc0[8*q8+4],acc0[8*q8+5]); u0.w = pk2(acc0[8*q8+6],acc0[8*q8+7]);
      u1.x = pk2(acc1[8*q8+0],acc1[8*q8+1]); u1.y = pk2(acc1[8*q8+2],acc1[8*q8+3]);
      u1.z = pk2(acc1[8*q8+4],acc1[8*q8+5]); u1.w = pk2(acc1[8*q8+6],acc1[8*q8+7]);
      *(uint4*)&r0[q8*8] = u0;
      *(uint4*)&r1[q8*8] = u1;
    }
    meta[w*128 + lane]      = make_float4(l0, best0, __int_as_float(bn0), 0.f);
    meta[w*128 + lane + 64] = make_float4(l1, best1, __int_as_float(bn1), 0.f);
  }
  __syncthreads();

  // ---- phase 2: every lane finalizes its 2 tokens (all 64 lanes active)
  #pragma unroll
  for (int which=0; which<2; ++which){
    int tokidx = lane + which*64;
    int t = g*128 + tokidx;
    const float* qv = which ? qv1 : qv0;
    int own = t >> 2, nvis = (t+1) >> 2;
    float out[32];
    float ll = 0.f, bb = -1e30f;
    int bn = (own==0) ? 1 : 0;       // jax top_k fallback (only reachable for t<4)
    #pragma unroll
    for (int d=0;d<32;d++) out[d]=0.f;
    #pragma unroll
    for (int sp=0; sp<4; ++sp){      // ascending split = ascending n: tie-break preserved
      const ushort* r = &accs[(sp*128 + tokidx)*40];
      #pragma unroll
      for (int q8=0; q8<4; q8++){
        uint4 u = *(const uint4*)&r[q8*8];
        out[8*q8+0]+=bflo(u.x); out[8*q8+1]+=bfhi(u.x);
        out[8*q8+2]+=bflo(u.y); out[8*q8+3]+=bfhi(u.y);
        out[8*q8+4]+=bflo(u.z); out[8*q8+5]+=bfhi(u.z);
        out[8*q8+6]+=bflo(u.w); out[8*q8+7]+=bfhi(u.w);
      }
      float4 m4 = meta[sp*128 + tokidx];
      ll += m4.x;
      if (m4.y > bb){ bb = m4.y; bn = __float_as_int(m4.z); }
    }
    const ushort* gr = vg + ((size_t)b*SEQ + t)*VGS + 256;
    float g0 = sigmoidf_(bf2f(gr[hh])), g1 = sigmoidf_(bf2f(gr[8+hh])), g2 = sigmoidf_(bf2f(gr[16+hh]));
    float inv = (nvis > 0) ? g0/ll : 0.f;
    #pragma unroll
    for (int d=0;d<32;d++) out[d] *= inv;

    // ---- selection branch: own block + best block, causal token mask
    float s2[8];
    float m2 = -1e30f;
    #pragma unroll
    for (int ki=0; ki<8; ++ki){
      int tt = (ki<4 ? own : bn)*4 + (ki&3);
      float s = -1e30f;
      if (tt <= t){
        const float* kr = kbase + (size_t)tt*QKS;
        float sv = 0.f;
        #pragma unroll
        for (int d=0; d<32; d+=4){
          float4 kv = *(const float4*)(kr + d);
          sv += qv[d]*kv.x + qv[d+1]*kv.y + qv[d+2]*kv.z + qv[d+3]*kv.w;
        }
        s = sv*SCALE;
        m2 = fmaxf(m2, s);
      }
      s2[ki] = s;
    }
    float l2 = 0.f;
    #pragma unroll
    for (int ki=0; ki<8; ++ki)
      if (s2[ki] > -1e29f) l2 += __expf(s2[ki] - m2);
    float inv2 = g1/l2;              // l2 >= 1 (self token always visible)
    #pragma unroll
    for (int ki=0; ki<8; ++ki){
      int tt = (ki<4 ? own : bn)*4 + (ki&3);
      if (tt <= t){
        float pw = __expf(s2[ki] - m2) * inv2;
        float vvv[32];
        #pragma unroll
        for (int d=0; d<32; d+=8) bf8_to_f32(vbase + (size_t)tt*VGS + d, &vvv[d]);
        #pragma unroll
        for (int d=0; d<32; d++) out[d] += pw*vvv[d];
      }
    }

    // ---- sliding window (W=2): tokens t-1, t
    int tp = (t>0) ? t-1 : 0;
    const float* ka = kbase + (size_t)tp*QKS;
    const float* kb2= kbase + (size_t)t *QKS;
    float sa=0.f, sb=0.f;
    #pragma unroll
    for (int d=0; d<32; d+=4){
      float4 k1 = *(const float4*)(ka + d);
      float4 k2 = *(const float4*)(kb2 + d);
      sa += qv[d]*k1.x + qv[d+1]*k1.y + qv[d+2]*k1.z + qv[d+3]*k1.w;
      sb += qv[d]*k2.x + qv[d+1]*k2.y + qv[d+2]*k2.z + qv[d+3]*k2.w;
    }
    sa *= SCALE; sb *= SCALE;
    float m3 = (t>0) ? fmaxf(sa, sb) : sb;
    float pa = (t>0) ? __expf(sa-m3) : 0.f;
    float pb = __expf(sb-m3);
    float inv3 = g2/(pa+pb);
    float va[32], vbv[32];
    #pragma unroll
    for (int d=0; d<32; d+=8){
      bf8_to_f32(vbase + (size_t)tp*VGS + d, &va[d]);
      bf8_to_f32(vbase + (size_t)t *VGS + d, &vbv[d]);
    }
    ushort* orow = o + ((size_t)b*SEQ + t)*DIM + hh*DH;
    #pragma unroll
    for (int d=0; d<32; d+=8){
      float r0[8];
      #pragma unroll
      for (int j=0;j<8;j++) r0[j] = out[d+j] + (pa*va[d+j] + pb*vbv[d+j])*inv3;
      uint4 u;
      u.x = pk2(r0[0], r0[1]);
      u.y = pk2(r0[2], r0[3]);
      u.z = pk2(r0[4], r0[5]);
      u.w = pk2(r0[6], r0[7]);
      *(uint4*)&orow[d] = u;
    }
  }
}

extern "C" void kernel_launch(void* const* d_in, const int* in_sizes, int n_in,
                              void* d_out, int out_size, void* d_ws, size_t ws_size,
                              hipStream_t stream) {
  const float* x_in   = (const float*)d_in[0];
  const float* ln_a_g = (const float*)d_in[1];
  const float* ln_a_b = (const float*)d_in[2];
  const float* Wq     = (const float*)d_in[3];
  const float* Wk     = (const float*)d_in[4];
  const float* Wv     = (const float*)d_in[5];
  const float* Wg     = (const float*)d_in[6];
  const float* Wo     = (const float*)d_in[7];
  const float* ln_f_g = (const float*)d_in[8];
  const float* ln_f_b = (const float*)d_in[9];
  const float* W1     = (const float*)d_in[10];
  const float* b1     = (const float*)d_in[11];
  const float* W2     = (const float*)d_in[12];
  const float* b2     = (const float*)d_in[13];

  float* xout = (float*)d_out;             // running residual stream [8192][256] f32
  float* ws = (float*)d_ws;
  const size_t NTOK = (size_t)BATCH*SEQ;   // 8192
  float* h    = ws;                                    // [8192][256] f32
  float* qkb  = h    + NTOK*DIM;                       // [8192][512] f32
  float* kcb  = qkb  + NTOK*QKS;                       // [4][8][512][32] f32
  float* vcb  = kcb  + (size_t)BATCH*NH*NB*DH;
  float* wqk  = vcb  + (size_t)BATCH*NH*NB*DH;         // [4][256][512] f32
  ushort* hb   = (ushort*)(wqk + (size_t)4*DIM*QKS);   // [8192][256] bf16
  ushort* vgu  = hb   + NTOK*DIM;                      // [8192][320] bf16
  ushort* obu  = vgu  + NTOK*VGS;                      // [8192][256] bf16
  ushort* midu = obu  + NTOK*DIM;                      // [8192][512] bf16
  ushort* wvgT = midu + NTOK*512;                      // [4][320][256] bf16
  ushort* woT  = wvgT + (size_t)4*VGS*DIM;             // [4][256][256] bf16
  ushort* w1T  = woT  + (size_t)4*DIM*DIM;             // [2][512][256] bf16
  ushort* w2T  = w1T  + (size_t)2*512*DIM;             // [2][256][512] bf16

  copy_f32<<<2048, 256, 0, stream>>>(x_in, xout, (int)(NTOK*DIM/4));
  build_wqk <<<(4*256*QKS+255)/256, 256, 0, stream>>>(Wq, Wk, wqk);
  build_wvgT<<<(4*VGS*256+255)/256, 256, 0, stream>>>(Wv, Wg, wvgT);
  build_wT  <<<(4*256*256+255)/256, 256, 0, stream>>>(Wo, woT, 4, 256, 256);
  build_wT  <<<(2*256*512+255)/256, 256, 0, stream>>>(W1, w1T, 2, 256, 512);
  build_wT  <<<(2*512*256+255)/256, 256, 0, stream>>>(W2, w2T, 2, 512, 256);

  dim3 gqk(64,8), gvg(64,5), g4(64,4), g8(64,8);
  for (int i=0;i<4;i++){
    ln_k<<<2048,256,0,stream>>>(xout, ln_a_g + i*DIM, ln_a_b + i*DIM, h, hb);
    gemm_f32<false,false,false><<<gqk,256,0,stream>>>(h, wqk + (size_t)i*DIM*QKS, nullptr, qkb, 8192,QKS,256);
    gemm_bf16<false,false,false,true><<<gvg,256,0,stream>>>(hb, wvgT + (size_t)i*VGS*DIM, nullptr, vgu, 8192,VGS,256);
    pool_k<<<2048,256,0,stream>>>(qkb, vgu, kcb, vcb);
    nsa_attn<<<512,256,0,stream>>>(qkb, vgu, kcb, vcb, obu);
    gemm_bf16<false,false,true,false><<<g4,256,0,stream>>>(obu, woT + (size_t)i*DIM*DIM, nullptr, xout, 8192,DIM,256);
    if (i & 1){
      int l = i >> 1;
      ln_k<<<2048,256,0,stream>>>(xout, ln_f_g + l*DIM, ln_f_b + l*DIM, h, hb);
      gemm_bf16<true,true,false,true><<<g8,256,0,stream>>>(hb,   w1T + (size_t)l*512*DIM, b1 + l*512, midu, 8192,512,256);
      gemm_bf16<true,false,true,false><<<g4,256,0,stream>>>(midu, w2T + (size_t)l*DIM*512, b2 + l*DIM, xout, 8192,DIM,512);
    }
  }
}

// Round 7
// 875.682 us; speedup vs baseline: 1.5399x; 1.0863x over previous
//
#include <hip/hip_runtime.h>
#include <hip/hip_bf16.h>
#include <math.h>

#define NH 8
#define DH 32
#define DIM 256
#define SEQ 2048
#define BATCH 4
#define NB 512            // SEQ / C
#define QKS 512           // q|k packed f32 row stride
#define VGS 320           // v|g packed bf16 row stride: 256 v | 24 g | 40 pad
#define SCALE 0.17677669529663687f  // DH^-0.5

typedef short short8v __attribute__((ext_vector_type(8)));
typedef float float4v __attribute__((ext_vector_type(4)));

__device__ __forceinline__ float sigmoidf_(float x){ return 1.f/(1.f+__expf(-x)); }
__device__ __forceinline__ ushort f2bf(float f){
  uint b = __float_as_uint(f);
  return (ushort)((b + 0x7fffu + ((b>>16)&1u)) >> 16);   // RNE
}
__device__ __forceinline__ float bf2f(ushort u){ return __uint_as_float(((uint)u)<<16); }
__device__ __forceinline__ float bflo(uint u){ return __uint_as_float(u<<16); }
__device__ __forceinline__ float bfhi(uint u){ return __uint_as_float(u & 0xffff0000u); }
__device__ __forceinline__ uint pk2(float a, float b){ return (uint)f2bf(a) | ((uint)f2bf(b)<<16); }
__device__ __forceinline__ void bfu4_to_f32(uint4 u, float* f){
  f[0]=bflo(u.x); f[1]=bfhi(u.x);
  f[2]=bflo(u.y); f[3]=bfhi(u.y);
  f[4]=bflo(u.z); f[5]=bfhi(u.z);
  f[6]=bflo(u.w); f[7]=bfhi(u.w);
}

// ---------------- copy (residual stream init) ----------------
__global__ void copy_f32(const float* __restrict__ in, float* __restrict__ out, int n4){
  int i = blockIdx.x*blockDim.x + threadIdx.x;
  if (i < n4) ((float4*)out)[i] = ((const float4*)in)[i];
}

// ---------------- weight packers ----------------
__global__ void build_wqk(const float* __restrict__ Wq, const float* __restrict__ Wk, float* __restrict__ out){
  int i = blockIdx.x*256 + threadIdx.x;          // 4*256*512
  if (i >= 4*256*QKS) return;
  int col = i & 511, rk = (i>>9)&255, l = i>>17;
  out[i] = (col < 256) ? Wq[((size_t)l*256+rk)*256+col] : Wk[((size_t)l*256+rk)*256+col-256];
}
__global__ void build_wvgT(const float* __restrict__ Wv, const float* __restrict__ Wg, ushort* __restrict__ out){
  int i = blockIdx.x*256 + threadIdx.x;          // 4*320*256 : out[l][n][k] = B[k][n]
  if (i >= 4*VGS*256) return;
  int k = i & 255, n = (i>>8)%VGS, l = i/(VGS*256);
  float v = 0.f;
  if      (n < 256) v = Wv[((size_t)l*256+k)*256+n];
  else if (n < 280) v = Wg[((size_t)l*256+k)*24 + (n-256)];
  out[i] = f2bf(v);
}
__global__ void build_wT(const float* __restrict__ in, ushort* __restrict__ out, int L, int K, int N){
  int i = blockIdx.x*256 + threadIdx.x;          // out[l][n][k] = in[l][k][n]
  if (i >= L*K*N) return;
  int k = i % K, n = (i/K) % N, l = i/(K*N);
  out[i] = f2bf(in[((size_t)l*K+k)*N+n]);
}

// ---------------- layernorm: one wave per row, dual f32+bf16 output ----------------
__global__ __launch_bounds__(256) void ln_k(const float* __restrict__ x, const float* __restrict__ g,
                                            const float* __restrict__ b, float* __restrict__ h,
                                            ushort* __restrict__ hb){
  int row  = blockIdx.x*4 + (threadIdx.x>>6);
  int lane = threadIdx.x & 63;
  int c = lane*4;
  const float* xr = x + (size_t)row*DIM + c;
  float4 v = *(const float4*)xr;
  float s = v.x+v.y+v.z+v.w;
  float q = v.x*v.x+v.y*v.y+v.z*v.z+v.w*v.w;
  #pragma unroll
  for (int off=32; off>0; off>>=1){ s += __shfl_xor(s, off); q += __shfl_xor(q, off); }
  float mean = s * (1.f/DIM);
  float var  = q * (1.f/DIM) - mean*mean;
  float rs = rsqrtf(var + 1e-5f);
  float4 gg = *(const float4*)(g + c);
  float4 bb = *(const float4*)(b + c);
  float4 o;
  o.x = (v.x-mean)*rs*gg.x + bb.x;
  o.y = (v.y-mean)*rs*gg.y + bb.y;
  o.z = (v.z-mean)*rs*gg.z + bb.z;
  o.w = (v.w-mean)*rs*gg.w + bb.w;
  *(float4*)(h + (size_t)row*DIM + c) = o;
  uint2 u;
  u.x = pk2(o.x, o.y);
  u.y = pk2(o.z, o.w);
  *(uint2*)&hb[(size_t)row*DIM + c] = u;
}

// ---------------- f32 GEMM (q|k path), guard-free, BK=32 ----------------
template<bool BIAS, bool LEAKY, bool ACC>
__global__ __launch_bounds__(256) void gemm_f32(const float* __restrict__ A, const float* __restrict__ B,
                                                const float* __restrict__ bias, float* __restrict__ C,
                                                int M, int N, int K){
  __shared__ float As[32][132];
  __shared__ float Bs[32][68];
  int tid = threadIdx.x;
  int m0 = blockIdx.x*128, n0 = blockIdx.y*64;
  int tx = tid & 15, ty = tid >> 4;
  int ar = tid >> 1;            // 0..127
  int ac = (tid & 1)*16;        // 0 or 16
  int bk = tid >> 3;            // 0..31
  int bn = (tid & 7)*8;         // 0..56
  const float* Ap = A + (size_t)(m0+ar)*K + ac;
  const float* Bp = B + (size_t)bk*N + n0 + bn;
  float4 apre[4], bpre[2];
  #pragma unroll
  for (int j=0;j<4;j++) apre[j] = *(const float4*)(Ap + 4*j);
  bpre[0] = *(const float4*)Bp;
  bpre[1] = *(const float4*)(Bp + 4);
  float acc[8][4];
  #pragma unroll
  for (int i=0;i<8;i++)
    #pragma unroll
    for (int j=0;j<4;j++) acc[i][j]=0.f;
  for (int k0=0; k0<K; k0+=32){
    #pragma unroll
    for (int j=0;j<4;j++){
      As[ac+4*j+0][ar]=apre[j].x; As[ac+4*j+1][ar]=apre[j].y;
      As[ac+4*j+2][ar]=apre[j].z; As[ac+4*j+3][ar]=apre[j].w;
    }
    *(float4*)&Bs[bk][bn]   = bpre[0];
    *(float4*)&Bs[bk][bn+4] = bpre[1];
    __syncthreads();
    if (k0 + 32 < K){
      #pragma unroll
      for (int j=0;j<4;j++) apre[j] = *(const float4*)(Ap + k0 + 32 + 4*j);
      bpre[0] = *(const float4*)(Bp + (size_t)(k0+32)*N);
      bpre[1] = *(const float4*)(Bp + (size_t)(k0+32)*N + 4);
    }
    #pragma unroll
    for (int kk=0;kk<32;kk++){
      float4 bv  = *(const float4*)&Bs[kk][tx*4];
      float4 av0 = *(const float4*)&As[kk][ty*8];
      float4 av1 = *(const float4*)&As[kk][ty*8+4];
      float av[8] = {av0.x,av0.y,av0.z,av0.w,av1.x,av1.y,av1.z,av1.w};
      float bw[4] = {bv.x,bv.y,bv.z,bv.w};
      #pragma unroll
      for (int i=0;i<8;i++)
        #pragma unroll
        for (int j=0;j<4;j++) acc[i][j] += av[i]*bw[j];
    }
    __syncthreads();
  }
  #pragma unroll
  for (int i=0;i<8;i++){
    int m = m0 + ty*8 + i;
    #pragma unroll
    for (int j=0;j<4;j++){
      int n = n0 + tx*4 + j;
      float val = acc[i][j];
      if (BIAS)  val += bias[n];
      if (LEAKY) val = val > 0.f ? val : 0.01f*val;
      float* cp = C + (size_t)m*N + n;
      if (ACC) val += *cp;
      *cp = val;
    }
  }
}

// ---------------- bf16 MFMA GEMM: C = act(A[M,K] @ Bt[N,K]^T + bias) ----------------
template<bool BIAS, bool LEAKY, bool ACC, bool OBF16>
__global__ __launch_bounds__(256) void gemm_bf16(const ushort* __restrict__ A, const ushort* __restrict__ Bt,
                                                 const float* __restrict__ bias, void* __restrict__ Cv,
                                                 int M, int N, int K){
  __shared__ ushort Al[128*64];
  __shared__ ushort Bl[64*64];
  int tid = threadIdx.x;
  int m0 = blockIdx.x*128, n0 = blockIdx.y*64;
  int w = tid>>6, lane = tid&63;
  int wm = w>>1, wn = w&1;
  float4v acc[4][2];
  #pragma unroll
  for (int i=0;i<4;i++)
    #pragma unroll
    for (int j=0;j<2;j++) acc[i][j] = (float4v){0.f,0.f,0.f,0.f};
  for (int k0=0; k0<K; k0+=64){
    #pragma unroll
    for (int i=0;i<4;i++){
      int id = tid + 256*i;
      int r = id>>3, c = id&7;
      *(uint4*)&Al[r*64 + ((c ^ (r&7))*8)] = *(const uint4*)&A[(size_t)(m0+r)*K + k0 + c*8];
    }
    #pragma unroll
    for (int i=0;i<2;i++){
      int id = tid + 256*i;
      int r = id>>3, c = id&7;
      *(uint4*)&Bl[r*64 + ((c ^ (r&7))*8)] = *(const uint4*)&Bt[(size_t)(n0+r)*K + k0 + c*8];
    }
    __syncthreads();
    #pragma unroll
    for (int kk=0; kk<2; ++kk){
      short8v a[4], bfr[2];
      #pragma unroll
      for (int mf=0; mf<4; mf++){
        int r = wm*64 + mf*16 + (lane&15);
        int c = (kk*4 + (lane>>4)) ^ (r&7);
        a[mf] = *(short8v*)&Al[r*64 + c*8];
      }
      #pragma unroll
      for (int nf=0; nf<2; nf++){
        int r = wn*32 + nf*16 + (lane&15);
        int c = (kk*4 + (lane>>4)) ^ (r&7);
        bfr[nf] = *(short8v*)&Bl[r*64 + c*8];
      }
      #pragma unroll
      for (int mf=0; mf<4; mf++)
        #pragma unroll
        for (int nf=0; nf<2; nf++)
          acc[mf][nf] = __builtin_amdgcn_mfma_f32_16x16x32_bf16(a[mf], bfr[nf], acc[mf][nf], 0, 0, 0);
    }
    __syncthreads();
  }
  #pragma unroll
  for (int nf=0; nf<2; nf++){
    int col = n0 + wn*32 + nf*16 + (lane&15);
    float bv = BIAS ? bias[col] : 0.f;
    #pragma unroll
    for (int mf=0; mf<4; mf++){
      #pragma unroll
      for (int r=0; r<4; r++){
        int row = m0 + wm*64 + mf*16 + (lane>>4)*4 + r;
        float vv = acc[mf][nf][r];
        if (BIAS) vv += bv;
        if (LEAKY) vv = vv > 0.f ? vv : 0.01f*vv;
        if (OBF16) ((ushort*)Cv)[(size_t)row*N + col] = f2bf(vv);
        else {
          float* C = (float*)Cv;
          if (ACC) vv += C[(size_t)row*N + col];
          C[(size_t)row*N + col] = vv;
        }
      }
    }
  }
}

// ---------------- mean-pool K/V blocks (C=4), output [b][h][n][32] f32 ----------------
__global__ void pool_k(const float* __restrict__ qk, const ushort* __restrict__ vg,
                       float* __restrict__ kc, float* __restrict__ vc){
  int i = blockIdx.x*256 + threadIdx.x;       // 0 .. B*H*NB*32-1
  if (i >= BATCH*NH*NB*DH) return;
  int d = i & 31, n = (i >> 5) & 511, h = (i >> 14) & 7, b = i >> 17;
  size_t kb = ((size_t)(b*SEQ + n*4))*QKS + 256 + h*DH + d;
  kc[i] = 0.25f*(qk[kb] + qk[kb+QKS] + qk[kb+2*QKS] + qk[kb+3*QKS]);
  size_t vb = ((size_t)(b*SEQ + n*4))*VGS + h*DH + d;
  vc[i] = 0.25f*(bf2f(vg[vb]) + bf2f(vg[vb+VGS]) + bf2f(vg[vb+2*VGS]) + bf2f(vg[vb+3*VGS]));
}

// ---------------- fused NSA attention v5 ----------------
// 32 groups x 64 tokens per (b,h). Grid 1024, 4 waves, 4-way n-split, 1 tok/lane.
// Block e: hh=e&7 (XCD slot), b=(e>>3)&3, q=(e>>5)&7, r=e>>8;
//   g = {31-q, q, 23-q, 8+q}[r]  -> bijective over 0..31, per-CU weight sum constant,
//   heavy rounds dispatched first. All 1024 blocks co-resident (20KB LDS, ~<=128 VGPR).
// Phase 1: wave w scans n-range [w*chunk,(w+1)*chunk), chunk=4(g+1); lane=token.
//   Compressed scores use the exact grouped-4 f32 dot (argmax path f32-stable).
//   Partials: acc->bf16 in LDS, (l,best,bestn) f32 meta.
// Phase 2: 4 lanes per token, d-split (8 dims each). Selection/window dots are
//   8-FMA partials + 2 shfl_xor within the 4-lane group (branch-uniform).
__global__ __launch_bounds__(256, 4) void nsa_attn(
    const float* __restrict__ qk, const ushort* __restrict__ vg,
    const float* __restrict__ kc, const float* __restrict__ vc,
    ushort* __restrict__ o)
{
  __shared__ ushort accs[4*64*32];   // 16 KB bf16 oc partials
  __shared__ float4 meta[4*64];      // 4 KB (l, best, bestn, -)
  int e = blockIdx.x;
  int hh = e & 7;
  int b  = (e >> 3) & 3;
  int qq = (e >> 5) & 7;
  int r  = e >> 8;
  int g  = (r==0) ? (31-qq) : (r==1) ? qq : (r==2) ? (23-qq) : (8+qq);
  int tid = threadIdx.x;
  int w = tid >> 6, lane = tid & 63;
  const float* kcg = kc + ((size_t)(b*NH + hh)*NB)*DH;
  const float* vcg = vc + ((size_t)(b*NH + hh)*NB)*DH;

  // ---- phase 1: lane = token
  {
    int t = g*64 + lane;
    int own = t >> 2, nvis = (t+1) >> 2;
    float qv[32];
    {
      const float4* qr = (const float4*)(qk + ((size_t)b*SEQ + t)*QKS + hh*DH);
      #pragma unroll
      for (int d8=0; d8<8; d8++){
        float4 a4 = qr[d8];
        qv[4*d8]=a4.x; qv[4*d8+1]=a4.y; qv[4*d8+2]=a4.z; qv[4*d8+3]=a4.w;
      }
    }
    int chunk = 4*(g+1);
    int n0 = w*chunk, n1 = n0 + chunk;
    float l = 0.f, best = -1e30f;
    int bn1 = -1;
    float acc[32];
    #pragma unroll
    for (int d=0;d<32;d++) acc[d]=0.f;
    for (int n=n0; n<n1; ++n){
      const float4* kp = (const float4*)(kcg + (size_t)n*DH);   // wave-uniform row
      float s = 0.f;
      #pragma unroll
      for (int d8=0; d8<8; d8++){
        float4 k4 = kp[d8];
        s += qv[4*d8]*k4.x + qv[4*d8+1]*k4.y + qv[4*d8+2]*k4.z + qv[4*d8+3]*k4.w;
      }
      s *= SCALE;
      bool act = (n < nvis);
      if (act && n != own && s > best){ best = s; bn1 = n; }  // strict > = lowest-index tie-break
      float p = act ? __expf(s) : 0.f;      // max-free: |s| small, exp safe
      l += p;
      const float4* vp = (const float4*)(vcg + (size_t)n*DH);
      #pragma unroll
      for (int d8=0; d8<8; d8++){
        float4 v4 = vp[d8];
        acc[4*d8]   += p*v4.x; acc[4*d8+1] += p*v4.y;
        acc[4*d8+2] += p*v4.z; acc[4*d8+3] += p*v4.w;
      }
    }
    ushort* pr = &accs[((size_t)w*64 + lane)*32];
    #pragma unroll
    for (int q8=0; q8<4; q8++){
      uint4 u;
      u.x = pk2(acc[8*q8+0],acc[8*q8+1]); u.y = pk2(acc[8*q8+2],acc[8*q8+3]);
      u.z = pk2(acc[8*q8+4],acc[8*q8+5]); u.w = pk2(acc[8*q8+6],acc[8*q8+7]);
      *(uint4*)&pr[q8*8] = u;
    }
    meta[w*64 + lane] = make_float4(l, best, __int_as_float(bn1), 0.f);
  }
  __syncthreads();

  // ---- phase 2: 4 lanes per token, d-split (8 dims per lane)
  {
    int tok = tid >> 2;
    int ds  = (tid & 3)*8;
    int t = g*64 + tok;
    int own = t >> 2, nvis = (t+1) >> 2;
    float q8[8];
    {
      const float4* qr = (const float4*)(qk + ((size_t)b*SEQ + t)*QKS + hh*DH + ds);
      float4 a4 = qr[0], b4 = qr[1];
      q8[0]=a4.x; q8[1]=a4.y; q8[2]=a4.z; q8[3]=a4.w;
      q8[4]=b4.x; q8[5]=b4.y; q8[6]=b4.z; q8[7]=b4.w;
    }
    float out8[8];
    #pragma unroll
    for (int j=0;j<8;j++) out8[j]=0.f;
    float ll = 0.f, bb = -1e30f;
    int bn = (own==0) ? 1 : 0;         // jax top_k fallback
    #pragma unroll
    for (int sp=0; sp<4; ++sp){        // ascending split = ascending n: tie-break preserved
      uint4 u = *(const uint4*)&accs[((size_t)sp*64 + tok)*32 + ds];
      float f[8]; bfu4_to_f32(u, f);
      #pragma unroll
      for (int j=0;j<8;j++) out8[j] += f[j];
      float4 m4 = meta[sp*64 + tok];
      ll += m4.x;
      if (m4.y > bb){ bb = m4.y; bn = __float_as_int(m4.z); }
    }
    const ushort* gr = vg + ((size_t)b*SEQ + t)*VGS + 256;
    float g0 = sigmoidf_(bf2f(gr[hh])), g1 = sigmoidf_(bf2f(gr[8+hh])), g2 = sigmoidf_(bf2f(gr[16+hh]));
    float inv = (nvis > 0) ? g0/ll : 0.f;
    #pragma unroll
    for (int j=0;j<8;j++) out8[j] *= inv;

    // selection branch: own block + best block, causal token mask, d-split dots
    const float*  kb2 = qk + (size_t)b*SEQ*QKS + 256 + hh*DH + ds;
    const ushort* vb2 = vg + (size_t)b*SEQ*VGS + hh*DH + ds;
    float s2[8];
    float m2 = -1e30f;
    #pragma unroll
    for (int ki=0; ki<8; ++ki){
      int tt = (ki<4 ? own : bn)*4 + (ki&3);
      float s = -1e30f;
      if (tt <= t){                       // uniform across the 4 lanes of this token
        const float4* kr = (const float4*)(kb2 + (size_t)tt*QKS);
        float4 a4 = kr[0], c4 = kr[1];
        float ps = q8[0]*a4.x + q8[1]*a4.y + q8[2]*a4.z + q8[3]*a4.w
                 + q8[4]*c4.x + q8[5]*c4.y + q8[6]*c4.z + q8[7]*c4.w;
        ps += __shfl_xor(ps, 1);
        ps += __shfl_xor(ps, 2);
        s = ps*SCALE;
        m2 = fmaxf(m2, s);
      }
      s2[ki] = s;
    }
    float l2 = 0.f;
    #pragma unroll
    for (int ki=0; ki<8; ++ki)
      if (s2[ki] > -1e29f) l2 += __expf(s2[ki] - m2);
    float inv2 = g1/l2;                   // l2 >= 1 (self token always visible)
    #pragma unroll
    for (int ki=0; ki<8; ++ki){
      int tt = (ki<4 ? own : bn)*4 + (ki&3);
      if (tt <= t){
        float pw = __expf(s2[ki] - m2) * inv2;
        uint4 u = *(const uint4*)(vb2 + (size_t)tt*VGS);
        float f[8]; bfu4_to_f32(u, f);
        #pragma unroll
        for (int j=0;j<8;j++) out8[j] += pw*f[j];
      }
    }

    // sliding window (W=2): tokens t-1, t
    int tp = (t>0) ? t-1 : 0;
    float sa, sb;
    {
      const float4* ka = (const float4*)(kb2 + (size_t)tp*QKS);
      const float4* kb4= (const float4*)(kb2 + (size_t)t *QKS);
      float4 a0 = ka[0], a1 = ka[1], b0 = kb4[0], b1 = kb4[1];
      float pa_ = q8[0]*a0.x + q8[1]*a0.y + q8[2]*a0.z + q8[3]*a0.w
                + q8[4]*a1.x + q8[5]*a1.y + q8[6]*a1.z + q8[7]*a1.w;
      float pb_ = q8[0]*b0.x + q8[1]*b0.y + q8[2]*b0.z + q8[3]*b0.w
                + q8[4]*b1.x + q8[5]*b1.y + q8[6]*b1.z + q8[7]*b1.w;
      pa_ += __shfl_xor(pa_, 1); pa_ += __shfl_xor(pa_, 2);
      pb_ += __shfl_xor(pb_, 1); pb_ += __shfl_xor(pb_, 2);
      sa = pa_*SCALE; sb = pb_*SCALE;
    }
    float m3 = (t>0) ? fmaxf(sa, sb) : sb;
    float pa = (t>0) ? __expf(sa-m3) : 0.f;
    float pb = __expf(sb-m3);
    float inv3 = g2/(pa+pb);
    float va[8], vbv[8];
    bfu4_to_f32(*(const uint4*)(vb2 + (size_t)tp*VGS), va);
    bfu4_to_f32(*(const uint4*)(vb2 + (size_t)t *VGS), vbv);
    ushort* orow = o + ((size_t)b*SEQ + t)*DIM + hh*DH + ds;
    float rr[8];
    #pragma unroll
    for (int j=0;j<8;j++) rr[j] = out8[j] + (pa*va[j] + pb*vbv[j])*inv3;
    uint4 u;
    u.x = pk2(rr[0], rr[1]);
    u.y = pk2(rr[2], rr[3]);
    u.z = pk2(rr[4], rr[5]);
    u.w = pk2(rr[6], rr[7]);
    *(uint4*)orow = u;
  }
}

extern "C" void kernel_launch(void* const* d_in, const int* in_sizes, int n_in,
                              void* d_out, int out_size, void* d_ws, size_t ws_size,
                              hipStream_t stream) {
  const float* x_in   = (const float*)d_in[0];
  const float* ln_a_g = (const float*)d_in[1];
  const float* ln_a_b = (const float*)d_in[2];
  const float* Wq     = (const float*)d_in[3];
  const float* Wk     = (const float*)d_in[4];
  const float* Wv     = (const float*)d_in[5];
  const float* Wg     = (const float*)d_in[6];
  const float* Wo     = (const float*)d_in[7];
  const float* ln_f_g = (const float*)d_in[8];
  const float* ln_f_b = (const float*)d_in[9];
  const float* W1     = (const float*)d_in[10];
  const float* b1     = (const float*)d_in[11];
  const float* W2     = (const float*)d_in[12];
  const float* b2     = (const float*)d_in[13];

  float* xout = (float*)d_out;             // running residual stream [8192][256] f32
  float* ws = (float*)d_ws;
  const size_t NTOK = (size_t)BATCH*SEQ;   // 8192
  float* h    = ws;                                    // [8192][256] f32
  float* qkb  = h    + NTOK*DIM;                       // [8192][512] f32
  float* kcb  = qkb  + NTOK*QKS;                       // [4][8][512][32] f32
  float* vcb  = kcb  + (size_t)BATCH*NH*NB*DH;
  float* wqk  = vcb  + (size_t)BATCH*NH*NB*DH;         // [4][256][512] f32
  ushort* hb   = (ushort*)(wqk + (size_t)4*DIM*QKS);   // [8192][256] bf16
  ushort* vgu  = hb   + NTOK*DIM;                      // [8192][320] bf16
  ushort* obu  = vgu  + NTOK*VGS;                      // [8192][256] bf16
  ushort* midu = obu  + NTOK*DIM;                      // [8192][512] bf16
  ushort* wvgT = midu + NTOK*512;                      // [4][320][256] bf16
  ushort* woT  = wvgT + (size_t)4*VGS*DIM;             // [4][256][256] bf16
  ushort* w1T  = woT  + (size_t)4*DIM*DIM;             // [2][512][256] bf16
  ushort* w2T  = w1T  + (size_t)2*512*DIM;             // [2][256][512] bf16

  copy_f32<<<2048, 256, 0, stream>>>(x_in, xout, (int)(NTOK*DIM/4));
  build_wqk <<<(4*256*QKS+255)/256, 256, 0, stream>>>(Wq, Wk, wqk);
  build_wvgT<<<(4*VGS*256+255)/256, 256, 0, stream>>>(Wv, Wg, wvgT);
  build_wT  <<<(4*256*256+255)/256, 256, 0, stream>>>(Wo, woT, 4, 256, 256);
  build_wT  <<<(2*256*512+255)/256, 256, 0, stream>>>(W1, w1T, 2, 256, 512);
  build_wT  <<<(2*512*256+255)/256, 256, 0, stream>>>(W2, w2T, 2, 512, 256);

  dim3 gqk(64,8), gvg(64,5), g4(64,4), g8(64,8);
  for (int i=0;i<4;i++){
    ln_k<<<2048,256,0,stream>>>(xout, ln_a_g + i*DIM, ln_a_b + i*DIM, h, hb);
    gemm_f32<false,false,false><<<gqk,256,0,stream>>>(h, wqk + (size_t)i*DIM*QKS, nullptr, qkb, 8192,QKS,256);
    gemm_bf16<false,false,false,true><<<gvg,256,0,stream>>>(hb, wvgT + (size_t)i*VGS*DIM, nullptr, vgu, 8192,VGS,256);
    pool_k<<<2048,256,0,stream>>>(qkb, vgu, kcb, vcb);
    nsa_attn<<<1024,256,0,stream>>>(qkb, vgu, kcb, vcb, obu);
    gemm_bf16<false,false,true,false><<<g4,256,0,stream>>>(obu, woT + (size_t)i*DIM*DIM, nullptr, xout, 8192,DIM,256);
    if (i & 1){
      int l = i >> 1;
      ln_k<<<2048,256,0,stream>>>(xout, ln_f_g + l*DIM, ln_f_b + l*DIM, h, hb);
      gemm_bf16<true,true,false,true><<<g8,256,0,stream>>>(hb,   w1T + (size_t)l*512*DIM, b1 + l*512, midu, 8192,512,256);
      gemm_bf16<true,false,true,false><<<g4,256,0,stream>>>(midu, w2T + (size_t)l*DIM*512, b2 + l*DIM, xout, 8192,DIM,512);
    }
  }
}

// Round 8
// 644.794 us; speedup vs baseline: 2.0914x; 1.3581x over previous
//
#include <hip/hip_runtime.h>
#include <hip/hip_bf16.h>
#include <math.h>

#define NH 8
#define DH 32
#define DIM 256
#define SEQ 2048
#define BATCH 4
#define NB 512            // SEQ / C
#define QKS 512           // q|k packed f32 row stride
#define VGS 320           // v|g packed bf16 row stride: 256 v | 24 g | 40 pad
#define SCALE 0.17677669529663687f  // DH^-0.5

typedef short short8v __attribute__((ext_vector_type(8)));
typedef float float4v __attribute__((ext_vector_type(4)));

__device__ __forceinline__ float sigmoidf_(float x){ return 1.f/(1.f+__expf(-x)); }
__device__ __forceinline__ ushort f2bf(float f){
  uint b = __float_as_uint(f);
  return (ushort)((b + 0x7fffu + ((b>>16)&1u)) >> 16);   // RNE
}
__device__ __forceinline__ float bf2f(ushort u){ return __uint_as_float(((uint)u)<<16); }
__device__ __forceinline__ float bflo(uint u){ return __uint_as_float(u<<16); }
__device__ __forceinline__ float bfhi(uint u){ return __uint_as_float(u & 0xffff0000u); }
__device__ __forceinline__ uint pk2(float a, float b){ return (uint)f2bf(a) | ((uint)f2bf(b)<<16); }
__device__ __forceinline__ void bfu4_to_f32(uint4 u, float* f){
  f[0]=bflo(u.x); f[1]=bfhi(u.x);
  f[2]=bflo(u.y); f[3]=bfhi(u.y);
  f[4]=bflo(u.z); f[5]=bfhi(u.z);
  f[6]=bflo(u.w); f[7]=bfhi(u.w);
}

// ---------------- copy (residual stream init) ----------------
__global__ void copy_f32(const float* __restrict__ in, float* __restrict__ out, int n4){
  int i = blockIdx.x*blockDim.x + threadIdx.x;
  if (i < n4) ((float4*)out)[i] = ((const float4*)in)[i];
}

// ---------------- weight packers ----------------
__global__ void build_wqk(const float* __restrict__ Wq, const float* __restrict__ Wk, float* __restrict__ out){
  int i = blockIdx.x*256 + threadIdx.x;          // 4*256*512
  if (i >= 4*256*QKS) return;
  int col = i & 511, rk = (i>>9)&255, l = i>>17;
  out[i] = (col < 256) ? Wq[((size_t)l*256+rk)*256+col] : Wk[((size_t)l*256+rk)*256+col-256];
}
__global__ void build_wvgT(const float* __restrict__ Wv, const float* __restrict__ Wg, ushort* __restrict__ out){
  int i = blockIdx.x*256 + threadIdx.x;          // 4*320*256 : out[l][n][k] = B[k][n]
  if (i >= 4*VGS*256) return;
  int k = i & 255, n = (i>>8)%VGS, l = i/(VGS*256);
  float v = 0.f;
  if      (n < 256) v = Wv[((size_t)l*256+k)*256+n];
  else if (n < 280) v = Wg[((size_t)l*256+k)*24 + (n-256)];
  out[i] = f2bf(v);
}
__global__ void build_wT(const float* __restrict__ in, ushort* __restrict__ out, int L, int K, int N){
  int i = blockIdx.x*256 + threadIdx.x;          // out[l][n][k] = in[l][k][n]
  if (i >= L*K*N) return;
  int k = i % K, n = (i/K) % N, l = i/(K*N);
  out[i] = f2bf(in[((size_t)l*K+k)*N+n]);
}

// ---------------- layernorm: one wave per row, dual f32+bf16 output ----------------
__global__ __launch_bounds__(256) void ln_k(const float* __restrict__ x, const float* __restrict__ g,
                                            const float* __restrict__ b, float* __restrict__ h,
                                            ushort* __restrict__ hb){
  int row  = blockIdx.x*4 + (threadIdx.x>>6);
  int lane = threadIdx.x & 63;
  int c = lane*4;
  const float* xr = x + (size_t)row*DIM + c;
  float4 v = *(const float4*)xr;
  float s = v.x+v.y+v.z+v.w;
  float q = v.x*v.x+v.y*v.y+v.z*v.z+v.w*v.w;
  #pragma unroll
  for (int off=32; off>0; off>>=1){ s += __shfl_xor(s, off); q += __shfl_xor(q, off); }
  float mean = s * (1.f/DIM);
  float var  = q * (1.f/DIM) - mean*mean;
  float rs = rsqrtf(var + 1e-5f);
  float4 gg = *(const float4*)(g + c);
  float4 bb = *(const float4*)(b + c);
  float4 o;
  o.x = (v.x-mean)*rs*gg.x + bb.x;
  o.y = (v.y-mean)*rs*gg.y + bb.y;
  o.z = (v.z-mean)*rs*gg.z + bb.z;
  o.w = (v.w-mean)*rs*gg.w + bb.w;
  *(float4*)(h + (size_t)row*DIM + c) = o;
  uint2 u;
  u.x = pk2(o.x, o.y);
  u.y = pk2(o.z, o.w);
  *(uint2*)&hb[(size_t)row*DIM + c] = u;
}

// ---------------- f32 GEMM (q|k path), guard-free, BK=32 ----------------
template<bool BIAS, bool LEAKY, bool ACC>
__global__ __launch_bounds__(256) void gemm_f32(const float* __restrict__ A, const float* __restrict__ B,
                                                const float* __restrict__ bias, float* __restrict__ C,
                                                int M, int N, int K){
  __shared__ float As[32][132];
  __shared__ float Bs[32][68];
  int tid = threadIdx.x;
  int m0 = blockIdx.x*128, n0 = blockIdx.y*64;
  int tx = tid & 15, ty = tid >> 4;
  int ar = tid >> 1;            // 0..127
  int ac = (tid & 1)*16;        // 0 or 16
  int bk = tid >> 3;            // 0..31
  int bn = (tid & 7)*8;         // 0..56
  const float* Ap = A + (size_t)(m0+ar)*K + ac;
  const float* Bp = B + (size_t)bk*N + n0 + bn;
  float4 apre[4], bpre[2];
  #pragma unroll
  for (int j=0;j<4;j++) apre[j] = *(const float4*)(Ap + 4*j);
  bpre[0] = *(const float4*)Bp;
  bpre[1] = *(const float4*)(Bp + 4);
  float acc[8][4];
  #pragma unroll
  for (int i=0;i<8;i++)
    #pragma unroll
    for (int j=0;j<4;j++) acc[i][j]=0.f;
  for (int k0=0; k0<K; k0+=32){
    #pragma unroll
    for (int j=0;j<4;j++){
      As[ac+4*j+0][ar]=apre[j].x; As[ac+4*j+1][ar]=apre[j].y;
      As[ac+4*j+2][ar]=apre[j].z; As[ac+4*j+3][ar]=apre[j].w;
    }
    *(float4*)&Bs[bk][bn]   = bpre[0];
    *(float4*)&Bs[bk][bn+4] = bpre[1];
    __syncthreads();
    if (k0 + 32 < K){
      #pragma unroll
      for (int j=0;j<4;j++) apre[j] = *(const float4*)(Ap + k0 + 32 + 4*j);
      bpre[0] = *(const float4*)(Bp + (size_t)(k0+32)*N);
      bpre[1] = *(const float4*)(Bp + (size_t)(k0+32)*N + 4);
    }
    #pragma unroll
    for (int kk=0;kk<32;kk++){
      float4 bv  = *(const float4*)&Bs[kk][tx*4];
      float4 av0 = *(const float4*)&As[kk][ty*8];
      float4 av1 = *(const float4*)&As[kk][ty*8+4];
      float av[8] = {av0.x,av0.y,av0.z,av0.w,av1.x,av1.y,av1.z,av1.w};
      float bw[4] = {bv.x,bv.y,bv.z,bv.w};
      #pragma unroll
      for (int i=0;i<8;i++)
        #pragma unroll
        for (int j=0;j<4;j++) acc[i][j] += av[i]*bw[j];
    }
    __syncthreads();
  }
  #pragma unroll
  for (int i=0;i<8;i++){
    int m = m0 + ty*8 + i;
    #pragma unroll
    for (int j=0;j<4;j++){
      int n = n0 + tx*4 + j;
      float val = acc[i][j];
      if (BIAS)  val += bias[n];
      if (LEAKY) val = val > 0.f ? val : 0.01f*val;
      float* cp = C + (size_t)m*N + n;
      if (ACC) val += *cp;
      *cp = val;
    }
  }
}

// ---------------- bf16 MFMA GEMM: C = act(A[M,K] @ Bt[N,K]^T + bias) ----------------
template<bool BIAS, bool LEAKY, bool ACC, bool OBF16>
__global__ __launch_bounds__(256) void gemm_bf16(const ushort* __restrict__ A, const ushort* __restrict__ Bt,
                                                 const float* __restrict__ bias, void* __restrict__ Cv,
                                                 int M, int N, int K){
  __shared__ ushort Al[128*64];
  __shared__ ushort Bl[64*64];
  int tid = threadIdx.x;
  int m0 = blockIdx.x*128, n0 = blockIdx.y*64;
  int w = tid>>6, lane = tid&63;
  int wm = w>>1, wn = w&1;
  float4v acc[4][2];
  #pragma unroll
  for (int i=0;i<4;i++)
    #pragma unroll
    for (int j=0;j<2;j++) acc[i][j] = (float4v){0.f,0.f,0.f,0.f};
  for (int k0=0; k0<K; k0+=64){
    #pragma unroll
    for (int i=0;i<4;i++){
      int id = tid + 256*i;
      int r = id>>3, c = id&7;
      *(uint4*)&Al[r*64 + ((c ^ (r&7))*8)] = *(const uint4*)&A[(size_t)(m0+r)*K + k0 + c*8];
    }
    #pragma unroll
    for (int i=0;i<2;i++){
      int id = tid + 256*i;
      int r = id>>3, c = id&7;
      *(uint4*)&Bl[r*64 + ((c ^ (r&7))*8)] = *(const uint4*)&Bt[(size_t)(n0+r)*K + k0 + c*8];
    }
    __syncthreads();
    #pragma unroll
    for (int kk=0; kk<2; ++kk){
      short8v a[4], bfr[2];
      #pragma unroll
      for (int mf=0; mf<4; mf++){
        int r = wm*64 + mf*16 + (lane&15);
        int c = (kk*4 + (lane>>4)) ^ (r&7);
        a[mf] = *(short8v*)&Al[r*64 + c*8];
      }
      #pragma unroll
      for (int nf=0; nf<2; nf++){
        int r = wn*32 + nf*16 + (lane&15);
        int c = (kk*4 + (lane>>4)) ^ (r&7);
        bfr[nf] = *(short8v*)&Bl[r*64 + c*8];
      }
      #pragma unroll
      for (int mf=0; mf<4; mf++)
        #pragma unroll
        for (int nf=0; nf<2; nf++)
          acc[mf][nf] = __builtin_amdgcn_mfma_f32_16x16x32_bf16(a[mf], bfr[nf], acc[mf][nf], 0, 0, 0);
    }
    __syncthreads();
  }
  #pragma unroll
  for (int nf=0; nf<2; nf++){
    int col = n0 + wn*32 + nf*16 + (lane&15);
    float bv = BIAS ? bias[col] : 0.f;
    #pragma unroll
    for (int mf=0; mf<4; mf++){
      #pragma unroll
      for (int r=0; r<4; r++){
        int row = m0 + wm*64 + mf*16 + (lane>>4)*4 + r;
        float vv = acc[mf][nf][r];
        if (BIAS) vv += bv;
        if (LEAKY) vv = vv > 0.f ? vv : 0.01f*vv;
        if (OBF16) ((ushort*)Cv)[(size_t)row*N + col] = f2bf(vv);
        else {
          float* C = (float*)Cv;
          if (ACC) vv += C[(size_t)row*N + col];
          C[(size_t)row*N + col] = vv;
        }
      }
    }
  }
}

// ---------------- mean-pool K/V blocks (C=4), output [b][h][n][32] f32 ----------------
__global__ void pool_k(const float* __restrict__ qk, const ushort* __restrict__ vg,
                       float* __restrict__ kc, float* __restrict__ vc){
  int i = blockIdx.x*256 + threadIdx.x;       // 0 .. B*H*NB*32-1
  if (i >= BATCH*NH*NB*DH) return;
  int d = i & 31, n = (i >> 5) & 511, h = (i >> 14) & 7, b = i >> 17;
  size_t kb = ((size_t)(b*SEQ + n*4))*QKS + 256 + h*DH + d;
  kc[i] = 0.25f*(qk[kb] + qk[kb+QKS] + qk[kb+2*QKS] + qk[kb+3*QKS]);
  size_t vb = ((size_t)(b*SEQ + n*4))*VGS + h*DH + d;
  vc[i] = 0.25f*(bf2f(vg[vb]) + bf2f(vg[vb+VGS]) + bf2f(vg[vb+2*VGS]) + bf2f(vg[vb+3*VGS]));
}

// ---------------- fused NSA attention v6: LDS-tiled compressed scan ----------------
// 32 groups x 64 tokens per (b,h). Grid 1024, 4 waves, 1 tok/lane (phase 1).
// Block e: hh=e&7 (XCD slot), b=(e>>3)&3, q=(e>>5)&7, r=e>>8;
//   g = {31-q, q, 23-q, 8+q}[r] -> bijective, per-CU weight ~constant, heavy first.
// Phase 1: loop over 64-row kc/vc tiles staged cooperatively in LDS (coalesced);
//   wave w processes rows n == w (mod 4) within each tile -> all waves active on
//   every tile. LDS reads are same-address broadcasts (conflict-free).
//   Scores keep the exact grouped-4 f32 dot (bitwise = prior rounds) -> argmax
//   preserved; cross-wave combine adds equal-score lower-n tie-break (strided split).
// Phase 2: 4 lanes per token, d-split (8 dims each), as R7.
__global__ __launch_bounds__(256, 4) void nsa_attn(
    const float* __restrict__ qk, const ushort* __restrict__ vg,
    const float* __restrict__ kc, const float* __restrict__ vc,
    ushort* __restrict__ o)
{
  __shared__ float  kt[64*32];       // 8 KB f32 kc tile
  __shared__ float  vt[64*32];       // 8 KB f32 vc tile
  __shared__ ushort accs[4*64*32];   // 16 KB bf16 oc partials
  __shared__ float4 meta[4*64];      // 4 KB (l, best, bestn, -)
  int e = blockIdx.x;
  int hh = e & 7;
  int b  = (e >> 3) & 3;
  int qq = (e >> 5) & 7;
  int r  = e >> 8;
  int g  = (r==0) ? (31-qq) : (r==1) ? qq : (r==2) ? (23-qq) : (8+qq);
  int tid = threadIdx.x;
  int w = tid >> 6, lane = tid & 63;
  const float* kcg = kc + ((size_t)(b*NH + hh)*NB)*DH;
  const float* vcg = vc + ((size_t)(b*NH + hh)*NB)*DH;

  // ---- phase 1: lane = token; tile loop over compressed rows
  {
    int t = g*64 + lane;
    int own = t >> 2, nvis = (t+1) >> 2;
    float qv[32];
    {
      const float4* qr = (const float4*)(qk + ((size_t)b*SEQ + t)*QKS + hh*DH);
      #pragma unroll
      for (int d8=0; d8<8; d8++){
        float4 a4 = qr[d8];
        qv[4*d8]=a4.x; qv[4*d8+1]=a4.y; qv[4*d8+2]=a4.z; qv[4*d8+3]=a4.w;
      }
    }
    float l = 0.f, best = -1e30f;
    int bn1 = -1;
    float acc[32];
    #pragma unroll
    for (int d=0;d<32;d++) acc[d]=0.f;

    int tiles = (g + 4) >> 2;             // ceil(16(g+1)/64)
    for (int ti=0; ti<tiles; ++ti){
      int base = ti*64;
      if (ti) __syncthreads();            // previous tile fully consumed
      {                                   // cooperative stage: 2+2 float4 per thread
        const float4* sk = (const float4*)(kcg + (size_t)base*DH);
        const float4* sv = (const float4*)(vcg + (size_t)base*DH);
        float4* dk = (float4*)kt;
        float4* dv = (float4*)vt;
        dk[tid]     = sk[tid];
        dk[tid+256] = sk[tid+256];
        dv[tid]     = sv[tid];
        dv[tid+256] = sv[tid+256];
      }
      __syncthreads();
      #pragma unroll 4
      for (int kk=0; kk<16; ++kk){
        int n = base + w + 4*kk;          // strided split: all waves active per tile
        const float4* kp = (const float4*)&kt[(w + 4*kk)*32];
        float s = 0.f;
        #pragma unroll
        for (int d8=0; d8<8; d8++){
          float4 k4 = kp[d8];
          s += qv[4*d8]*k4.x + qv[4*d8+1]*k4.y + qv[4*d8+2]*k4.z + qv[4*d8+3]*k4.w;
        }
        s *= SCALE;
        bool act = (n < nvis);
        if (act && n != own && s > best){ best = s; bn1 = n; }  // ascending n in-wave
        float p = act ? __expf(s) : 0.f;  // max-free: |s| small, exp safe
        l += p;
        const float4* vp = (const float4*)&vt[(w + 4*kk)*32];
        #pragma unroll
        for (int d8=0; d8<8; d8++){
          float4 v4 = vp[d8];
          acc[4*d8]   += p*v4.x; acc[4*d8+1] += p*v4.y;
          acc[4*d8+2] += p*v4.z; acc[4*d8+3] += p*v4.w;
        }
      }
    }
    ushort* pr = &accs[((size_t)w*64 + lane)*32];
    #pragma unroll
    for (int q8=0; q8<4; q8++){
      uint4 u;
      u.x = pk2(acc[8*q8+0],acc[8*q8+1]); u.y = pk2(acc[8*q8+2],acc[8*q8+3]);
      u.z = pk2(acc[8*q8+4],acc[8*q8+5]); u.w = pk2(acc[8*q8+6],acc[8*q8+7]);
      *(uint4*)&pr[q8*8] = u;
    }
    meta[w*64 + lane] = make_float4(l, best, __int_as_float(bn1), 0.f);
  }
  __syncthreads();

  // ---- phase 2: 4 lanes per token, d-split (8 dims per lane)
  {
    int tok = tid >> 2;
    int ds  = (tid & 3)*8;
    int t = g*64 + tok;
    int own = t >> 2, nvis = (t+1) >> 2;
    float q8[8];
    {
      const float4* qr = (const float4*)(qk + ((size_t)b*SEQ + t)*QKS + hh*DH + ds);
      float4 a4 = qr[0], b4 = qr[1];
      q8[0]=a4.x; q8[1]=a4.y; q8[2]=a4.z; q8[3]=a4.w;
      q8[4]=b4.x; q8[5]=b4.y; q8[6]=b4.z; q8[7]=b4.w;
    }
    float out8[8];
    #pragma unroll
    for (int j=0;j<8;j++) out8[j]=0.f;
    float ll = 0.f, bb = -1e30f;
    int bn = (own==0) ? 1 : 0;         // jax top_k fallback
    #pragma unroll
    for (int sp=0; sp<4; ++sp){
      uint4 u = *(const uint4*)&accs[((size_t)sp*64 + tok)*32 + ds];
      float f[8]; bfu4_to_f32(u, f);
      #pragma unroll
      for (int j=0;j<8;j++) out8[j] += f[j];
      float4 m4 = meta[sp*64 + tok];
      ll += m4.x;
      int mi = __float_as_int(m4.z);
      // strided split: equal scores must resolve to the lower n (mi>=0 excludes empties)
      if (m4.y > bb || (m4.y == bb && mi >= 0 && mi < bn)){ bb = m4.y; bn = mi; }
    }
    const ushort* gr = vg + ((size_t)b*SEQ + t)*VGS + 256;
    float g0 = sigmoidf_(bf2f(gr[hh])), g1 = sigmoidf_(bf2f(gr[8+hh])), g2 = sigmoidf_(bf2f(gr[16+hh]));
    float inv = (nvis > 0) ? g0/ll : 0.f;
    #pragma unroll
    for (int j=0;j<8;j++) out8[j] *= inv;

    // selection branch: own block + best block, causal token mask, d-split dots
    const float*  kb2 = qk + (size_t)b*SEQ*QKS + 256 + hh*DH + ds;
    const ushort* vb2 = vg + (size_t)b*SEQ*VGS + hh*DH + ds;
    float s2[8];
    float m2 = -1e30f;
    #pragma unroll
    for (int ki=0; ki<8; ++ki){
      int tt = (ki<4 ? own : bn)*4 + (ki&3);
      float s = -1e30f;
      if (tt <= t){                       // uniform across the 4 lanes of this token
        const float4* kr = (const float4*)(kb2 + (size_t)tt*QKS);
        float4 a4 = kr[0], c4 = kr[1];
        float ps = q8[0]*a4.x + q8[1]*a4.y + q8[2]*a4.z + q8[3]*a4.w
                 + q8[4]*c4.x + q8[5]*c4.y + q8[6]*c4.z + q8[7]*c4.w;
        ps += __shfl_xor(ps, 1);
        ps += __shfl_xor(ps, 2);
        s = ps*SCALE;
        m2 = fmaxf(m2, s);
      }
      s2[ki] = s;
    }
    float l2 = 0.f;
    #pragma unroll
    for (int ki=0; ki<8; ++ki)
      if (s2[ki] > -1e29f) l2 += __expf(s2[ki] - m2);
    float inv2 = g1/l2;                   // l2 >= 1 (self token always visible)
    #pragma unroll
    for (int ki=0; ki<8; ++ki){
      int tt = (ki<4 ? own : bn)*4 + (ki&3);
      if (tt <= t){
        float pw = __expf(s2[ki] - m2) * inv2;
        uint4 u = *(const uint4*)(vb2 + (size_t)tt*VGS);
        float f[8]; bfu4_to_f32(u, f);
        #pragma unroll
        for (int j=0;j<8;j++) out8[j] += pw*f[j];
      }
    }

    // sliding window (W=2): tokens t-1, t
    int tp = (t>0) ? t-1 : 0;
    float sa, sb;
    {
      const float4* ka = (const float4*)(kb2 + (size_t)tp*QKS);
      const float4* kb4= (const float4*)(kb2 + (size_t)t *QKS);
      float4 a0 = ka[0], a1 = ka[1], b0 = kb4[0], b1 = kb4[1];
      float pa_ = q8[0]*a0.x + q8[1]*a0.y + q8[2]*a0.z + q8[3]*a0.w
                + q8[4]*a1.x + q8[5]*a1.y + q8[6]*a1.z + q8[7]*a1.w;
      float pb_ = q8[0]*b0.x + q8[1]*b0.y + q8[2]*b0.z + q8[3]*b0.w
                + q8[4]*b1.x + q8[5]*b1.y + q8[6]*b1.z + q8[7]*b1.w;
      pa_ += __shfl_xor(pa_, 1); pa_ += __shfl_xor(pa_, 2);
      pb_ += __shfl_xor(pb_, 1); pb_ += __shfl_xor(pb_, 2);
      sa = pa_*SCALE; sb = pb_*SCALE;
    }
    float m3 = (t>0) ? fmaxf(sa, sb) : sb;
    float pa = (t>0) ? __expf(sa-m3) : 0.f;
    float pb = __expf(sb-m3);
    float inv3 = g2/(pa+pb);
    float va[8], vbv[8];
    bfu4_to_f32(*(const uint4*)(vb2 + (size_t)tp*VGS), va);
    bfu4_to_f32(*(const uint4*)(vb2 + (size_t)t *VGS), vbv);
    ushort* orow = o + ((size_t)b*SEQ + t)*DIM + hh*DH + ds;
    float rr[8];
    #pragma unroll
    for (int j=0;j<8;j++) rr[j] = out8[j] + (pa*va[j] + pb*vbv[j])*inv3;
    uint4 u;
    u.x = pk2(rr[0], rr[1]);
    u.y = pk2(rr[2], rr[3]);
    u.z = pk2(rr[4], rr[5]);
    u.w = pk2(rr[6], rr[7]);
    *(uint4*)orow = u;
  }
}

extern "C" void kernel_launch(void* const* d_in, const int* in_sizes, int n_in,
                              void* d_out, int out_size, void* d_ws, size_t ws_size,
                              hipStream_t stream) {
  const float* x_in   = (const float*)d_in[0];
  const float* ln_a_g = (const float*)d_in[1];
  const float* ln_a_b = (const float*)d_in[2];
  const float* Wq     = (const float*)d_in[3];
  const float* Wk     = (const float*)d_in[4];
  const float* Wv     = (const float*)d_in[5];
  const float* Wg     = (const float*)d_in[6];
  const float* Wo     = (const float*)d_in[7];
  const float* ln_f_g = (const float*)d_in[8];
  const float* ln_f_b = (const float*)d_in[9];
  const float* W1     = (const float*)d_in[10];
  const float* b1     = (const float*)d_in[11];
  const float* W2     = (const float*)d_in[12];
  const float* b2     = (const float*)d_in[13];

  float* xout = (float*)d_out;             // running residual stream [8192][256] f32
  float* ws = (float*)d_ws;
  const size_t NTOK = (size_t)BATCH*SEQ;   // 8192
  float* h    = ws;                                    // [8192][256] f32
  float* qkb  = h    + NTOK*DIM;                       // [8192][512] f32
  float* kcb  = qkb  + NTOK*QKS;                       // [4][8][512][32] f32
  float* vcb  = kcb  + (size_t)BATCH*NH*NB*DH;
  float* wqk  = vcb  + (size_t)BATCH*NH*NB*DH;         // [4][256][512] f32
  ushort* hb   = (ushort*)(wqk + (size_t)4*DIM*QKS);   // [8192][256] bf16
  ushort* vgu  = hb   + NTOK*DIM;                      // [8192][320] bf16
  ushort* obu  = vgu  + NTOK*VGS;                      // [8192][256] bf16
  ushort* midu = obu  + NTOK*DIM;                      // [8192][512] bf16
  ushort* wvgT = midu + NTOK*512;                      // [4][320][256] bf16
  ushort* woT  = wvgT + (size_t)4*VGS*DIM;             // [4][256][256] bf16
  ushort* w1T  = woT  + (size_t)4*DIM*DIM;             // [2][512][256] bf16
  ushort* w2T  = w1T  + (size_t)2*512*DIM;             // [2][256][512] bf16

  copy_f32<<<2048, 256, 0, stream>>>(x_in, xout, (int)(NTOK*DIM/4));
  build_wqk <<<(4*256*QKS+255)/256, 256, 0, stream>>>(Wq, Wk, wqk);
  build_wvgT<<<(4*VGS*256+255)/256, 256, 0, stream>>>(Wv, Wg, wvgT);
  build_wT  <<<(4*256*256+255)/256, 256, 0, stream>>>(Wo, woT, 4, 256, 256);
  build_wT  <<<(2*256*512+255)/256, 256, 0, stream>>>(W1, w1T, 2, 256, 512);
  build_wT  <<<(2*512*256+255)/256, 256, 0, stream>>>(W2, w2T, 2, 512, 256);

  dim3 gqk(64,8), gvg(64,5), g4(64,4), g8(64,8);
  for (int i=0;i<4;i++){
    ln_k<<<2048,256,0,stream>>>(xout, ln_a_g + i*DIM, ln_a_b + i*DIM, h, hb);
    gemm_f32<false,false,false><<<gqk,256,0,stream>>>(h, wqk + (size_t)i*DIM*QKS, nullptr, qkb, 8192,QKS,256);
    gemm_bf16<false,false,false,true><<<gvg,256,0,stream>>>(hb, wvgT + (size_t)i*VGS*DIM, nullptr, vgu, 8192,VGS,256);
    pool_k<<<2048,256,0,stream>>>(qkb, vgu, kcb, vcb);
    nsa_attn<<<1024,256,0,stream>>>(qkb, vgu, kcb, vcb, obu);
    gemm_bf16<false,false,true,false><<<g4,256,0,stream>>>(obu, woT + (size_t)i*DIM*DIM, nullptr, xout, 8192,DIM,256);
    if (i & 1){
      int l = i >> 1;
      ln_k<<<2048,256,0,stream>>>(xout, ln_f_g + l*DIM, ln_f_b + l*DIM, h, hb);
      gemm_bf16<true,true,false,true><<<g8,256,0,stream>>>(hb,   w1T + (size_t)l*512*DIM, b1 + l*512, midu, 8192,512,256);
      gemm_bf16<true,false,true,false><<<g4,256,0,stream>>>(midu, w2T + (size_t)l*DIM*512, b2 + l*DIM, xout, 8192,DIM,512);
    }
  }
}